// Round 8
// baseline (166.256 us; speedup 1.0000x reference)
//
#include <hip/hip_runtime.h>
#include <hip/hip_bf16.h>

#define NB 4
#define SEQ 2048
#define NHEADS 8
#define ROWS (NB * SEQ)

typedef __attribute__((ext_vector_type(8))) short bf16x8;
typedef __attribute__((ext_vector_type(4))) short bf16x4;
typedef __attribute__((ext_vector_type(4))) float f32x4;
typedef __attribute__((ext_vector_type(16))) float f32x16;

__device__ inline short f2bf(float x) {
    union { float f; unsigned u; } v; v.f = x;
    unsigned r = v.u + 0x7FFF + ((v.u >> 16) & 1);
    return (short)(r >> 16);
}

__device__ inline unsigned pack2bf(float a, float b) {
    __hip_bfloat162 h = __float22bfloat162_rn(make_float2(a, b));
    unsigned u; __builtin_memcpy(&u, &h, 4);
    return u;
}

// combine two packed-bf16 pairs from the two K-halves and scale: bf16 out
__device__ inline unsigned comb2(unsigned w1, unsigned w2, float inv) {
    union { unsigned v; float f; } a, b, c, d;
    a.v = w1 << 16;          b.v = w2 << 16;
    c.v = w1 & 0xffff0000u;  d.v = w2 & 0xffff0000u;
    return pack2bf((a.f + b.f) * inv, (c.f + d.f) * inv);
}

// ---------------------------------------------------------------------------
// Fused fp32 -> bf16 cast for all 5 inputs (one launch). Unit = 4 elements.
// x 524288 | ctx 524288 | Wq 32768 | Wkv 65536 | Wo 32768 -> 1179648 units.
// ---------------------------------------------------------------------------
__global__ __launch_bounds__(256) void cvt_all(
    const float* __restrict__ x, const float* __restrict__ ctx,
    const float* __restrict__ wq, const float* __restrict__ wkv,
    const float* __restrict__ wo,
    short* __restrict__ xb, short* __restrict__ cb, short* __restrict__ wqb,
    short* __restrict__ wkvb, short* __restrict__ wob)
{
    const int i = blockIdx.x * 256 + threadIdx.x;
    const float* src; short* dst; int off;
    if (i < 524288)       { src = x;   dst = xb;   off = i; }
    else if (i < 1048576) { src = ctx; dst = cb;   off = i - 524288; }
    else if (i < 1081344) { src = wq;  dst = wqb;  off = i - 1048576; }
    else if (i < 1146880) { src = wkv; dst = wkvb; off = i - 1081344; }
    else                  { src = wo;  dst = wob;  off = i - 1146880; }
    const float4 v = ((const float4*)src)[off];
    uint2 o2;
    o2.x = pack2bf(v.x, v.y);
    o2.y = pack2bf(v.z, v.w);
    *(uint2*)(dst + (size_t)off * 4) = o2;
}

// ---------------------------------------------------------------------------
// Merged q+kv projection, pure bf16, 128x128 tiles, BK=64, K=256.
// Grid 768: bid<512 -> kv tile (col=bid&7, row=bid>>3, Ccols=1024);
//           bid>=512 -> q tile (u=bid-512, col=u&3, row=u>>2, Ccols=512,
//           output pre-scaled by qscale = 0.125*log2e).
// 4 waves in 2x2, each 64x64. XOR-swizzled unpadded LDS; register prefetch.
// ---------------------------------------------------------------------------
__global__ __launch_bounds__(256, 3) void proj2(
    const short* __restrict__ xb, const short* __restrict__ wqb,
    const float* __restrict__ bq,
    const short* __restrict__ cb, const short* __restrict__ wkvb,
    const float* __restrict__ bkv,
    short* __restrict__ q2b, short* __restrict__ kv2b, float qscale)
{
    __shared__ short As[128 * 64];
    __shared__ short Ws[128 * 64];
    const int tid = threadIdx.x;
    const int bid = blockIdx.x;
    const int w = tid >> 6, lane = tid & 63, low = lane & 15, quad = lane >> 4;
    const int wm = w >> 1, wn = w & 1;
    const int K = 256;

    const short* A; const short* W; const float* bias;
    short* outp; int Ccols; float scale; int rM0, c0;
    if (bid < 512) {
        A = cb; W = wkvb; bias = bkv; outp = kv2b; Ccols = 1024; scale = 1.0f;
        c0 = (bid & 7) * 128; rM0 = (bid >> 3) * 128;
    } else {
        const int u = bid - 512;
        A = xb; W = wqb; bias = bq; outp = q2b; Ccols = 512; scale = qscale;
        c0 = (u & 3) * 128; rM0 = (u >> 2) * 128;
    }

    const int srow = tid >> 3, sj = tid & 7;

    f32x4 acc[4][4];
#pragma unroll
    for (int mt = 0; mt < 4; ++mt)
#pragma unroll
        for (int nt = 0; nt < 4; ++nt) acc[mt][nt] = (f32x4){0.f, 0.f, 0.f, 0.f};

    bf16x8 pab[4], pwb[4];
#pragma unroll
    for (int c = 0; c < 4; ++c) {
        const int row = c * 32 + srow;
        pab[c] = *(const bf16x8*)(A + (size_t)(rM0 + row) * K + sj * 8);
        pwb[c] = *(const bf16x8*)(W + (size_t)(c0 + row) * K + sj * 8);
    }

    int k0 = 0;
    for (;;) {
        __syncthreads();
#pragma unroll
        for (int c = 0; c < 4; ++c) {
            const int row = c * 32 + srow;
            const int pc = sj ^ (row & 7);
            *(bf16x8*)(&As[row * 64 + pc * 8]) = pab[c];
            *(bf16x8*)(&Ws[row * 64 + pc * 8]) = pwb[c];
        }
        __syncthreads();
        const int kn = k0 + 64;
        if (kn < K) {
#pragma unroll
            for (int c = 0; c < 4; ++c) {
                const int row = c * 32 + srow;
                pab[c] = *(const bf16x8*)(A + (size_t)(rM0 + row) * K + kn + sj * 8);
                pwb[c] = *(const bf16x8*)(W + (size_t)(c0 + row) * K + kn + sj * 8);
            }
        }
#pragma unroll
        for (int kh = 0; kh < 2; ++kh) {
            bf16x8 af[4], bfv[4];
#pragma unroll
            for (int t = 0; t < 4; ++t) {
                const int ra = wm * 64 + t * 16 + low;
                af[t] = *(const bf16x8*)(&As[ra * 64 + ((kh * 4 + quad) ^ (ra & 7)) * 8]);
                const int rb = wn * 64 + t * 16 + low;
                bfv[t] = *(const bf16x8*)(&Ws[rb * 64 + ((kh * 4 + quad) ^ (rb & 7)) * 8]);
            }
#pragma unroll
            for (int mt = 0; mt < 4; ++mt)
#pragma unroll
                for (int nt = 0; nt < 4; ++nt)
                    acc[mt][nt] = __builtin_amdgcn_mfma_f32_16x16x32_bf16(af[mt], bfv[nt], acc[mt][nt], 0, 0, 0);
        }
        k0 = kn;
        if (k0 >= K) break;
    }

#pragma unroll
    for (int nt = 0; nt < 4; ++nt) {
        const int col = c0 + wn * 64 + nt * 16 + low;
        const float bv = bias[col];
#pragma unroll
        for (int mt = 0; mt < 4; ++mt) {
            const size_t rbase = (size_t)(rM0 + wm * 64 + mt * 16 + quad * 4);
#pragma unroll
            for (int r = 0; r < 4; ++r)
                outp[(rbase + r) * Ccols + col] = f2bf((acc[mt][nt][r] + bv) * scale);
        }
    }
}

// ---------------------------------------------------------------------------
// o-GEMM with fused split-K combine, all-bf16 staging (Wo pre-cast):
// A[r][e] = (num1[r][e]+num2[r][e]) / (l1[r][h]+l2[r][h]), h = e/64.
// ---------------------------------------------------------------------------
__global__ __launch_bounds__(256) void gemm64_ocomb(
    const short* __restrict__ num, const float* __restrict__ lbuf,
    const short* __restrict__ W, const float* __restrict__ bias,
    float* __restrict__ out)
{
    const int K = 512, Ccols = 256;
    const size_t NHALF = (size_t)ROWS * 512;
    const int R8 = ROWS * 8;
    __shared__ short As[64 * 64];
    __shared__ short Ws[64 * 64];
    const int tid = threadIdx.x;
    const int w = tid >> 6, lane = tid & 63, low = lane & 15, quad = lane >> 4;
    const int wm = w >> 1, wn = w & 1;
    const int r0 = blockIdx.y * 64, c0 = blockIdx.x * 64;
    const int srow = tid >> 2;
    const int sc = (tid & 3) * 2;

    f32x4 acc[2][2];
#pragma unroll
    for (int mt = 0; mt < 2; ++mt)
#pragma unroll
        for (int nt = 0; nt < 2; ++nt) acc[mt][nt] = (f32x4){0.f, 0.f, 0.f, 0.f};

    uint4 pa1[2], pa2[2];
    float pinv;
    bf16x8 pwb[2];

    auto loadA = [&](int k0) {
        const int hh = k0 >> 6;
        const int row = r0 + srow;
        pinv = lbuf[row * 8 + hh] + lbuf[R8 + row * 8 + hh];
        const short* p1 = num + (size_t)row * 512 + k0 + sc * 8;
        pa1[0] = ((const uint4*)p1)[0];
        pa1[1] = ((const uint4*)p1)[1];
        const short* p2 = p1 + NHALF;
        pa2[0] = ((const uint4*)p2)[0];
        pa2[1] = ((const uint4*)p2)[1];
    };
    auto loadW = [&](int k0) {
        const short* p = W + (size_t)(c0 + srow) * K + k0 + sc * 8;
        pwb[0] = ((const bf16x8*)p)[0];
        pwb[1] = ((const bf16x8*)p)[1];
    };

    loadA(0); loadW(0);

    int k0 = 0;
    for (;;) {
        __syncthreads();
        {
            const float inv = 1.f / pinv;
#pragma unroll
            for (int c = 0; c < 2; ++c) {
                const int pc = (sc + c) ^ (srow & 7);
                union { unsigned u[4]; bf16x8 v; } r;
                r.u[0] = comb2(pa1[c].x, pa2[c].x, inv);
                r.u[1] = comb2(pa1[c].y, pa2[c].y, inv);
                r.u[2] = comb2(pa1[c].z, pa2[c].z, inv);
                r.u[3] = comb2(pa1[c].w, pa2[c].w, inv);
                *(bf16x8*)(&As[srow * 64 + pc * 8]) = r.v;
                *(bf16x8*)(&Ws[srow * 64 + pc * 8]) = pwb[c];
            }
        }
        __syncthreads();
        const int kn = k0 + 64;
        if (kn < K) { loadA(kn); loadW(kn); }
#pragma unroll
        for (int kh = 0; kh < 2; ++kh) {
            bf16x8 af[2], bfv[2];
#pragma unroll
            for (int t = 0; t < 2; ++t) {
                const int ra = wm * 32 + t * 16 + low;
                af[t] = *(const bf16x8*)(&As[ra * 64 + ((kh * 4 + quad) ^ (ra & 7)) * 8]);
                const int rb = wn * 32 + t * 16 + low;
                bfv[t] = *(const bf16x8*)(&Ws[rb * 64 + ((kh * 4 + quad) ^ (rb & 7)) * 8]);
            }
#pragma unroll
            for (int mt = 0; mt < 2; ++mt)
#pragma unroll
                for (int nt = 0; nt < 2; ++nt)
                    acc[mt][nt] = __builtin_amdgcn_mfma_f32_16x16x32_bf16(af[mt], bfv[nt], acc[mt][nt], 0, 0, 0);
        }
        k0 = kn;
        if (k0 >= K) break;
    }

#pragma unroll
    for (int nt = 0; nt < 2; ++nt) {
        const int col = c0 + wn * 32 + nt * 16 + low;
        const float bv = bias[col];
#pragma unroll
        for (int mt = 0; mt < 2; ++mt) {
            const size_t rbase = (size_t)(r0 + wm * 32 + mt * 16 + quad * 4);
#pragma unroll
            for (int r = 0; r < 4; ++r)
                out[(rbase + r) * Ccols + col] = acc[mt][nt][r] + bv;
        }
    }
}

// ---------------------------------------------------------------------------
// MFMA flash attention (32x32x16): split-K x2 over keys, XCD-swizzled 1-D
// grid, reads pre-projected/pre-scaled q2.
// v4 structure: coalesced K/V staging through LDS, double-buffered Ks/Vt
// ping-pong -> ONE __syncthreads per key-tile (T14 async-STAGE split:
// global loads issued at top of iter, LDS writes after PV, barrier last).
// ROUND-6 LESSON: hipcc's launch_bounds 2nd arg N budgets ~512/(2N) VGPRs:
// (256,4)->64, (256,3)->84 (measured). v4's live set is ~114 VGPRs
// (oacc 32 + qr 16 + pk/pv 16 + pfrag 16 + s 16 + wv 8 + addr ~10), so
// (256,4) spilled ~13 MB/dispatch (WRITE_SIZE 33.8 vs 20.5 MB legit).
// (256,2) -> ~128 budget: no spill; residency stays 4 blocks/CU because
// LDS caps it anyway (36864 B x 4 = 147 KB <= 160 KB).
// ROUND-4 LESSON: K-direct-from-global falsified (uncoalesced, 121.6 us).
// P stays in registers via cvt_pk + v_permlane32_swap_b32 (T12, round 0).
// Layouts (32x32x16, verified m74/m101):
//   A: A[m = lane&31][k = (lane>>5)*8 + j]
//   B: B[k = (lane>>5)*8 + j][n = lane&31]
//   C: col(n) = lane&31, row(m) = (reg&3) + 8*(reg>>2) + 4*(lane>>5)
// ---------------------------------------------------------------------------
#define KST 72
#define VST 72

__global__ __launch_bounds__(256, 2) void attn_mfma(
    const short* __restrict__ q2,   // ROWS x 512 bf16 (pre-scaled)
    const short* __restrict__ kv2,  // ROWS x 1024 bf16
    short* __restrict__ numb,       // 2 x ROWS x 512 bf16 (unnormalized O)
    float* __restrict__ lbuf)       // 2 x ROWS x 8 fp32
{
    __shared__ short Ks[2][64 * KST];
    __shared__ short Vt[2][64 * VST];

    const int tid = threadIdx.x;
    const int w = tid >> 6;
    const int lane = tid & 63;
    const int l31 = lane & 31;
    const int h2 = lane >> 5;

    // XCD swizzle decode
    const int flat = blockIdx.x;
    const int h = flat & 7;
    const int rest = flat >> 3;
    const int half = rest & 1;
    const int rest2 = rest >> 1;
    const int qtile = rest2 & 15;
    const int b = rest2 >> 4;
    const int iq0 = qtile * 128;
    const int jt0 = half * 16;

    // --- Q fragments: B operand, 4 k-steps, registers all kernel ---
    bf16x8 qr[4];
#pragma unroll
    for (int st = 0; st < 4; ++st)
        qr[st] = *(const bf16x8*)(q2 + (size_t)(b * SEQ + iq0 + w * 32 + l31) * 512
                                  + h * 64 + st * 16 + h2 * 8);

    const short* kbase = kv2 + (size_t)(b * SEQ) * 1024 + h * 64;
    const short* vbase = kbase + 512;

    float lsum = 0.f;                 // partial: query = l31, this lane's keys
    f32x16 oacc[2];                   // [dg]; col = dim, rows = queries
#pragma unroll
    for (int dg = 0; dg < 2; ++dg)
#pragma unroll
        for (int r = 0; r < 16; ++r) oacc[dg][r] = 0.f;

    // staging indices (coalesced: consecutive tids -> consecutive 32B in row)
    const int krow = tid >> 2;          // key row 0..63
    const int kc = (tid & 3) * 16;      // dim chunk (shorts)
    const int vk4 = (tid & 15) * 4;     // key base (V^T)
    const int vd4 = (tid >> 4) * 4;     // dim base 0..60

    // --- prefetch regs + first tile load ---
    bf16x8 pk0, pk1;
    bf16x4 pv0, pv1, pv2, pv3;
    {
        const short* ksrc = kbase + (size_t)(jt0 * 64 + krow) * 1024 + kc;
        pk0 = *(const bf16x8*)(ksrc);
        pk1 = *(const bf16x8*)(ksrc + 8);
        const short* vs = vbase + (size_t)(jt0 * 64 + vk4) * 1024 + vd4;
        pv0 = *(const bf16x4*)(vs);
        pv1 = *(const bf16x4*)(vs + 1024);
        pv2 = *(const bf16x4*)(vs + 2048);
        pv3 = *(const bf16x4*)(vs + 3072);
    }
    // --- stage first tile into buffer 0 ---
    *(bf16x8*)(&Ks[0][krow * KST + kc]) = pk0;
    *(bf16x8*)(&Ks[0][krow * KST + kc + 8]) = pk1;
    {
        bf16x4 c0_, c1_, c2_, c3_;
        c0_[0] = pv0[0]; c0_[1] = pv1[0]; c0_[2] = pv2[0]; c0_[3] = pv3[0];
        c1_[0] = pv0[1]; c1_[1] = pv1[1]; c1_[2] = pv2[1]; c1_[3] = pv3[1];
        c2_[0] = pv0[2]; c2_[1] = pv1[2]; c2_[2] = pv2[2]; c2_[3] = pv3[2];
        c3_[0] = pv0[3]; c3_[1] = pv1[3]; c3_[2] = pv2[3]; c3_[3] = pv3[3];
        short* Vn = &Vt[0][0];
        *(bf16x4*)(&Vn[(vd4 + 0) * VST + vk4]) = c0_;
        *(bf16x4*)(&Vn[(vd4 + 1) * VST + vk4]) = c1_;
        *(bf16x4*)(&Vn[(vd4 + 2) * VST + vk4]) = c2_;
        *(bf16x4*)(&Vn[(vd4 + 3) * VST + vk4]) = c3_;
    }
    __syncthreads();

    int buf = 0;
    for (int jt = jt0; jt < jt0 + 16; ++jt) {
        const bool notlast = (jt + 1 < jt0 + 16);

        // --- issue next-tile global loads early; latency hides under
        //     QK^T + softmax + PV (T14 async-STAGE split) ---
        if (notlast) {
            const short* ksrc = kbase + (size_t)((jt + 1) * 64 + krow) * 1024 + kc;
            pk0 = *(const bf16x8*)(ksrc);
            pk1 = *(const bf16x8*)(ksrc + 8);
            const short* vs = vbase + (size_t)((jt + 1) * 64 + vk4) * 1024 + vd4;
            pv0 = *(const bf16x4*)(vs);
            pv1 = *(const bf16x4*)(vs + 1024);
            pv2 = *(const bf16x4*)(vs + 2048);
            pv3 = *(const bf16x4*)(vs + 3072);
        }

        // --- S^T = K Q^T (2 key-groups x 4 k-steps); P stays in registers ---
        const short* Kc = &Ks[buf][0];
        bf16x8 pfrag[4];
#pragma unroll
        for (int kg = 0; kg < 2; ++kg) {
            f32x16 s;
#pragma unroll
            for (int r = 0; r < 16; ++r) s[r] = 0.f;
#pragma unroll
            for (int st = 0; st < 4; ++st) {
                const bf16x8 kf = *(const bf16x8*)(&Kc[(kg * 32 + l31) * KST + st * 16 + h2 * 8]);
                s = __builtin_amdgcn_mfma_f32_32x32x16_bf16(kf, qr[st], s, 0, 0, 0);
            }
            // exp2 + pack pairs: wv[2g]   = keys (8g+4*h2, 8g+1+4*h2)
            //                    wv[2g+1] = keys (8g+2+4*h2, 8g+3+4*h2)
            unsigned wv[8];
#pragma unroll
            for (int g = 0; g < 4; ++g) {
                const float p0 = __builtin_amdgcn_exp2f(s[4 * g + 0]);
                const float p1 = __builtin_amdgcn_exp2f(s[4 * g + 1]);
                const float p2 = __builtin_amdgcn_exp2f(s[4 * g + 2]);
                const float p3 = __builtin_amdgcn_exp2f(s[4 * g + 3]);
                lsum += (p0 + p1) + (p2 + p3);
                wv[2 * g]     = pack2bf(p0, p1);
                wv[2 * g + 1] = pack2bf(p2, p3);
            }
            // v_permlane32_swap_b32: lane l <-> l+32 (same query row l31).
            // swap(wv0,wv2) -> A-words 0,2 ; swap(wv1,wv3) -> A-words 1,3
#pragma unroll
            for (int q = 0; q < 2; ++q) {
                unsigned a0 = wv[4 * q + 0], b0 = wv[4 * q + 2];
                unsigned a1 = wv[4 * q + 1], b1 = wv[4 * q + 3];
                asm volatile("v_permlane32_swap_b32 %0, %1" : "+v"(a0), "+v"(b0));
                asm volatile("v_permlane32_swap_b32 %0, %1" : "+v"(a1), "+v"(b1));
                union { unsigned u[4]; bf16x8 v; } f;
                f.u[0] = a0; f.u[1] = a1; f.u[2] = b0; f.u[3] = b1;
                pfrag[kg * 2 + q] = f.v;
            }
        }

        // --- O += P V (4 k-steps x 2 dim-groups), P from regs, V from Vt[buf]
        const short* Vc = &Vt[buf][0];
#pragma unroll
        for (int st = 0; st < 4; ++st) {
            const bf16x8 pf = pfrag[st];
#pragma unroll
            for (int dg = 0; dg < 2; ++dg) {
                const bf16x8 vf = *(const bf16x8*)(&Vc[(dg * 32 + l31) * VST + st * 16 + h2 * 8]);
                oacc[dg] = __builtin_amdgcn_mfma_f32_32x32x16_bf16(pf, vf, oacc[dg], 0, 0, 0);
            }
        }

        // --- stage next tile into the other buffer; ONE barrier per iter ---
        if (notlast) {
            *(bf16x8*)(&Ks[buf ^ 1][krow * KST + kc]) = pk0;
            *(bf16x8*)(&Ks[buf ^ 1][krow * KST + kc + 8]) = pk1;
            bf16x4 c0_, c1_, c2_, c3_;
            c0_[0] = pv0[0]; c0_[1] = pv1[0]; c0_[2] = pv2[0]; c0_[3] = pv3[0];
            c1_[0] = pv0[1]; c1_[1] = pv1[1]; c1_[2] = pv2[1]; c1_[3] = pv3[1];
            c2_[0] = pv0[2]; c2_[1] = pv1[2]; c2_[2] = pv2[2]; c2_[3] = pv3[2];
            c3_[0] = pv0[3]; c3_[1] = pv1[3]; c3_[2] = pv2[3]; c3_[3] = pv3[3];
            short* Vn = &Vt[buf ^ 1][0];
            *(bf16x4*)(&Vn[(vd4 + 0) * VST + vk4]) = c0_;
            *(bf16x4*)(&Vn[(vd4 + 1) * VST + vk4]) = c1_;
            *(bf16x4*)(&Vn[(vd4 + 2) * VST + vk4]) = c2_;
            *(bf16x4*)(&Vn[(vd4 + 3) * VST + vk4]) = c3_;
        }
        __syncthreads();
        buf ^= 1;
    }

    // --- epilogue: combine h2 halves of lsum; store partial l and O ---
    lsum += __shfl_xor(lsum, 32);     // all 64 keys for query = w*32 + l31
    short* nb = numb + (size_t)half * ROWS * 512;
    float* lb = lbuf + (size_t)half * ROWS * 8;
    if (lane < 32)
        lb[(size_t)(b * SEQ + iq0 + w * 32 + l31) * 8 + h] = lsum;
#pragma unroll
    for (int dg = 0; dg < 2; ++dg)
#pragma unroll
        for (int r = 0; r < 16; ++r) {
            const int qrow = w * 32 + (r & 3) + 8 * (r >> 2) + 4 * h2;
            nb[(size_t)(b * SEQ + iq0 + qrow) * 512 + h * 64 + dg * 32 + l31] =
                f2bf(oacc[dg][r]);
        }
}

// ---------------------------------------------------------------------------
extern "C" void kernel_launch(void* const* d_in, const int* in_sizes, int n_in,
                              void* d_out, int out_size, void* d_ws, size_t ws_size,
                              hipStream_t stream) {
    const float* x   = (const float*)d_in[0];  // (4,2048,256)
    const float* ctx = (const float*)d_in[1];  // (4,2048,256)
    const float* Wq  = (const float*)d_in[2];  // (512,256)
    const float* bq  = (const float*)d_in[3];
    const float* Wkv = (const float*)d_in[4];  // (1024,256)
    const float* bkv = (const float*)d_in[5];
    const float* Wo  = (const float*)d_in[6];  // (256,512)
    const float* bo  = (const float*)d_in[7];
    float* out = (float*)d_out;                // (4,2048,256) fp32

    short* xb   = (short*)d_ws;                         // ROWS*256
    short* cb   = xb + (size_t)ROWS * 256;              // ROWS*256
    short* wqb  = cb + (size_t)ROWS * 256;              // 131072
    short* wkvb = wqb + 131072;                         // 262144
    short* wob  = wkvb + 262144;                        // 131072
    short* q2b  = wob + 131072;                         // ROWS*512
    short* kv2b = q2b + (size_t)ROWS * 512;             // ROWS*1024
    short* numb = kv2b + (size_t)ROWS * 1024;           // 2*ROWS*512
    float* lbuf = (float*)(numb + (size_t)2 * ROWS * 512); // 2*ROWS*8

    const float qscale = 0.125f * 1.44269504088896f;   // softmax scale + log2e

    cvt_all<<<4608, 256, 0, stream>>>(x, ctx, Wq, Wkv, Wo,
                                      xb, cb, wqb, wkvb, wob);
    // merged q+kv projection, 128x128 tiles, pure bf16 (768 blocks = 3/CU)
    proj2<<<768, 256, 0, stream>>>(xb, wqb, bq, cb, wkvb, bkv,
                                   q2b, kv2b, qscale);
    // attention, split-K x2, 32x32x16 MFMA, XCD-swizzled 1-D grid (1024 blocks)
    attn_mfma<<<NB * NHEADS * (SEQ / 128) * 2, 256, 0, stream>>>(
        q2b, kv2b, numb, lbuf);
    // out = combine(num1,num2)/(l1+l2) * Wo^T + bo (bf16 Wo)
    gemm64_ocomb<<<dim3(256 / 64, ROWS / 64), 256, 0, stream>>>(
        numb, lbuf, wob, bo, out);
}

// Round 9
// 164.457 us; speedup vs baseline: 1.0109x; 1.0109x over previous
//
#include <hip/hip_runtime.h>
#include <hip/hip_bf16.h>

#define NB 4
#define SEQ 2048
#define NHEADS 8
#define ROWS (NB * SEQ)

typedef __attribute__((ext_vector_type(8))) short bf16x8;
typedef __attribute__((ext_vector_type(4))) short bf16x4;
typedef __attribute__((ext_vector_type(4))) float f32x4;
typedef __attribute__((ext_vector_type(16))) float f32x16;

__device__ inline short f2bf(float x) {
    union { float f; unsigned u; } v; v.f = x;
    unsigned r = v.u + 0x7FFF + ((v.u >> 16) & 1);
    return (short)(r >> 16);
}

__device__ inline unsigned pack2bf(float a, float b) {
    __hip_bfloat162 h = __float22bfloat162_rn(make_float2(a, b));
    unsigned u; __builtin_memcpy(&u, &h, 4);
    return u;
}

// combine NS packed-bf16 pairs (one per split-K slab) and scale: bf16 out
template<int NS>
__device__ inline unsigned combN(const unsigned* w, float inv) {
    float lo = 0.f, hi = 0.f;
#pragma unroll
    for (int s = 0; s < NS; ++s) {
        union { unsigned v; float f; } a, b;
        a.v = w[s] << 16;          // low bf16 -> f32
        b.v = w[s] & 0xffff0000u;  // high bf16 -> f32
        lo += a.f; hi += b.f;
    }
    return pack2bf(lo * inv, hi * inv);
}

// ---------------------------------------------------------------------------
// Fused fp32 -> bf16 cast for all 5 inputs (one launch). Unit = 4 elements.
// x 524288 | ctx 524288 | Wq 32768 | Wkv 65536 | Wo 32768 -> 1179648 units.
// ---------------------------------------------------------------------------
__global__ __launch_bounds__(256) void cvt_all(
    const float* __restrict__ x, const float* __restrict__ ctx,
    const float* __restrict__ wq, const float* __restrict__ wkv,
    const float* __restrict__ wo,
    short* __restrict__ xb, short* __restrict__ cb, short* __restrict__ wqb,
    short* __restrict__ wkvb, short* __restrict__ wob)
{
    const int i = blockIdx.x * 256 + threadIdx.x;
    const float* src; short* dst; int off;
    if (i < 524288)       { src = x;   dst = xb;   off = i; }
    else if (i < 1048576) { src = ctx; dst = cb;   off = i - 524288; }
    else if (i < 1081344) { src = wq;  dst = wqb;  off = i - 1048576; }
    else if (i < 1146880) { src = wkv; dst = wkvb; off = i - 1081344; }
    else                  { src = wo;  dst = wob;  off = i - 1146880; }
    const float4 v = ((const float4*)src)[off];
    uint2 o2;
    o2.x = pack2bf(v.x, v.y);
    o2.y = pack2bf(v.z, v.w);
    *(uint2*)(dst + (size_t)off * 4) = o2;
}

// ---------------------------------------------------------------------------
// Merged q+kv projection, pure bf16, 128x128 tiles, BK=64, K=256.
// Grid 768: bid<512 -> kv tile (col=bid&7, row=bid>>3, Ccols=1024);
//           bid>=512 -> q tile (u=bid-512, col=u&3, row=u>>2, Ccols=512,
//           output pre-scaled by qscale = 0.125*log2e).
// 4 waves in 2x2, each 64x64. XOR-swizzled unpadded LDS; register prefetch.
// ---------------------------------------------------------------------------
__global__ __launch_bounds__(256, 3) void proj2(
    const short* __restrict__ xb, const short* __restrict__ wqb,
    const float* __restrict__ bq,
    const short* __restrict__ cb, const short* __restrict__ wkvb,
    const float* __restrict__ bkv,
    short* __restrict__ q2b, short* __restrict__ kv2b, float qscale)
{
    __shared__ short As[128 * 64];
    __shared__ short Ws[128 * 64];
    const int tid = threadIdx.x;
    const int bid = blockIdx.x;
    const int w = tid >> 6, lane = tid & 63, low = lane & 15, quad = lane >> 4;
    const int wm = w >> 1, wn = w & 1;
    const int K = 256;

    const short* A; const short* W; const float* bias;
    short* outp; int Ccols; float scale; int rM0, c0;
    if (bid < 512) {
        A = cb; W = wkvb; bias = bkv; outp = kv2b; Ccols = 1024; scale = 1.0f;
        c0 = (bid & 7) * 128; rM0 = (bid >> 3) * 128;
    } else {
        const int u = bid - 512;
        A = xb; W = wqb; bias = bq; outp = q2b; Ccols = 512; scale = qscale;
        c0 = (u & 3) * 128; rM0 = (u >> 2) * 128;
    }

    const int srow = tid >> 3, sj = tid & 7;

    f32x4 acc[4][4];
#pragma unroll
    for (int mt = 0; mt < 4; ++mt)
#pragma unroll
        for (int nt = 0; nt < 4; ++nt) acc[mt][nt] = (f32x4){0.f, 0.f, 0.f, 0.f};

    bf16x8 pab[4], pwb[4];
#pragma unroll
    for (int c = 0; c < 4; ++c) {
        const int row = c * 32 + srow;
        pab[c] = *(const bf16x8*)(A + (size_t)(rM0 + row) * K + sj * 8);
        pwb[c] = *(const bf16x8*)(W + (size_t)(c0 + row) * K + sj * 8);
    }

    int k0 = 0;
    for (;;) {
        __syncthreads();
#pragma unroll
        for (int c = 0; c < 4; ++c) {
            const int row = c * 32 + srow;
            const int pc = sj ^ (row & 7);
            *(bf16x8*)(&As[row * 64 + pc * 8]) = pab[c];
            *(bf16x8*)(&Ws[row * 64 + pc * 8]) = pwb[c];
        }
        __syncthreads();
        const int kn = k0 + 64;
        if (kn < K) {
#pragma unroll
            for (int c = 0; c < 4; ++c) {
                const int row = c * 32 + srow;
                pab[c] = *(const bf16x8*)(A + (size_t)(rM0 + row) * K + kn + sj * 8);
                pwb[c] = *(const bf16x8*)(W + (size_t)(c0 + row) * K + kn + sj * 8);
            }
        }
#pragma unroll
        for (int kh = 0; kh < 2; ++kh) {
            bf16x8 af[4], bfv[4];
#pragma unroll
            for (int t = 0; t < 4; ++t) {
                const int ra = wm * 64 + t * 16 + low;
                af[t] = *(const bf16x8*)(&As[ra * 64 + ((kh * 4 + quad) ^ (ra & 7)) * 8]);
                const int rb = wn * 64 + t * 16 + low;
                bfv[t] = *(const bf16x8*)(&Ws[rb * 64 + ((kh * 4 + quad) ^ (rb & 7)) * 8]);
            }
#pragma unroll
            for (int mt = 0; mt < 4; ++mt)
#pragma unroll
                for (int nt = 0; nt < 4; ++nt)
                    acc[mt][nt] = __builtin_amdgcn_mfma_f32_16x16x32_bf16(af[mt], bfv[nt], acc[mt][nt], 0, 0, 0);
        }
        k0 = kn;
        if (k0 >= K) break;
    }

#pragma unroll
    for (int nt = 0; nt < 4; ++nt) {
        const int col = c0 + wn * 64 + nt * 16 + low;
        const float bv = bias[col];
#pragma unroll
        for (int mt = 0; mt < 4; ++mt) {
            const size_t rbase = (size_t)(rM0 + wm * 64 + mt * 16 + quad * 4);
#pragma unroll
            for (int r = 0; r < 4; ++r)
                outp[(rbase + r) * Ccols + col] = f2bf((acc[mt][nt][r] + bv) * scale);
        }
    }
}

// ---------------------------------------------------------------------------
// o-GEMM with fused split-K combine over NS slabs, all-bf16 staging:
// A[r][e] = (sum_s num_s[r][e]) / (sum_s l_s[r][h]), h = e/64.
// ---------------------------------------------------------------------------
template<int NS>
__global__ __launch_bounds__(256) void gemm64_ocomb(
    const short* __restrict__ num, const float* __restrict__ lbuf,
    const short* __restrict__ W, const float* __restrict__ bias,
    float* __restrict__ out)
{
    const int K = 512, Ccols = 256;
    const size_t NSLAB = (size_t)ROWS * 512;
    const int R8 = ROWS * 8;
    __shared__ short As[64 * 64];
    __shared__ short Ws[64 * 64];
    const int tid = threadIdx.x;
    const int w = tid >> 6, lane = tid & 63, low = lane & 15, quad = lane >> 4;
    const int wm = w >> 1, wn = w & 1;
    const int r0 = blockIdx.y * 64, c0 = blockIdx.x * 64;
    const int srow = tid >> 2;
    const int sc = (tid & 3) * 2;

    f32x4 acc[2][2];
#pragma unroll
    for (int mt = 0; mt < 2; ++mt)
#pragma unroll
        for (int nt = 0; nt < 2; ++nt) acc[mt][nt] = (f32x4){0.f, 0.f, 0.f, 0.f};

    uint4 pa[NS][2];
    float pinv;
    bf16x8 pwb[2];

    auto loadA = [&](int k0) {
        const int hh = k0 >> 6;
        const int row = r0 + srow;
        float l = 0.f;
#pragma unroll
        for (int s = 0; s < NS; ++s) l += lbuf[s * R8 + row * 8 + hh];
        pinv = l;
#pragma unroll
        for (int s = 0; s < NS; ++s) {
            const short* p = num + s * NSLAB + (size_t)row * 512 + k0 + sc * 8;
            pa[s][0] = ((const uint4*)p)[0];
            pa[s][1] = ((const uint4*)p)[1];
        }
    };
    auto loadW = [&](int k0) {
        const short* p = W + (size_t)(c0 + srow) * K + k0 + sc * 8;
        pwb[0] = ((const bf16x8*)p)[0];
        pwb[1] = ((const bf16x8*)p)[1];
    };

    loadA(0); loadW(0);

    int k0 = 0;
    for (;;) {
        __syncthreads();
        {
            const float inv = 1.f / pinv;
#pragma unroll
            for (int c = 0; c < 2; ++c) {
                const int pc = (sc + c) ^ (srow & 7);
                unsigned w0[NS], w1[NS], w2[NS], w3[NS];
#pragma unroll
                for (int s = 0; s < NS; ++s) {
                    w0[s] = pa[s][c].x; w1[s] = pa[s][c].y;
                    w2[s] = pa[s][c].z; w3[s] = pa[s][c].w;
                }
                union { unsigned u[4]; bf16x8 v; } r;
                r.u[0] = combN<NS>(w0, inv);
                r.u[1] = combN<NS>(w1, inv);
                r.u[2] = combN<NS>(w2, inv);
                r.u[3] = combN<NS>(w3, inv);
                *(bf16x8*)(&As[srow * 64 + pc * 8]) = r.v;
                *(bf16x8*)(&Ws[srow * 64 + pc * 8]) = pwb[c];
            }
        }
        __syncthreads();
        const int kn = k0 + 64;
        if (kn < K) { loadA(kn); loadW(kn); }
#pragma unroll
        for (int kh = 0; kh < 2; ++kh) {
            bf16x8 af[2], bfv[2];
#pragma unroll
            for (int t = 0; t < 2; ++t) {
                const int ra = wm * 32 + t * 16 + low;
                af[t] = *(const bf16x8*)(&As[ra * 64 + ((kh * 4 + quad) ^ (ra & 7)) * 8]);
                const int rb = wn * 32 + t * 16 + low;
                bfv[t] = *(const bf16x8*)(&Ws[rb * 64 + ((kh * 4 + quad) ^ (rb & 7)) * 8]);
            }
#pragma unroll
            for (int mt = 0; mt < 2; ++mt)
#pragma unroll
                for (int nt = 0; nt < 2; ++nt)
                    acc[mt][nt] = __builtin_amdgcn_mfma_f32_16x16x32_bf16(af[mt], bfv[nt], acc[mt][nt], 0, 0, 0);
        }
        k0 = kn;
        if (k0 >= K) break;
    }

#pragma unroll
    for (int nt = 0; nt < 2; ++nt) {
        const int col = c0 + wn * 32 + nt * 16 + low;
        const float bv = bias[col];
#pragma unroll
        for (int mt = 0; mt < 2; ++mt) {
            const size_t rbase = (size_t)(r0 + wm * 32 + mt * 16 + quad * 4);
#pragma unroll
            for (int r = 0; r < 4; ++r)
                out[(rbase + r) * Ccols + col] = acc[mt][nt][r] + bv;
        }
    }
}

// ---------------------------------------------------------------------------
// MFMA flash attention (32x32x16): split-K x NS over keys, XCD-swizzled 1-D
// grid, reads pre-projected/pre-scaled q2. Body = round-1 structure exactly
// (single-buffered Ks/Vt, 2 barriers/iter, coalesced staging, P in regs via
// cvt_pk + v_permlane32_swap_b32) -- measured 55.4 us / VGPR 60 / 18KB at
// NS=2.
// ROUND-8 LESSON: 1-barrier double-buffer (36KB LDS) measured CLEAN at 70.2
// us -- occupancy 29.6->21.7% (LDS cap 8->4 blocks/CU). In-block pipelining
// falsified; cross-block TLP is the lever. Round-1 resources (18KB, 60 VGPR)
// allow 8 blocks/CU; grid 1024 (=4/CU) was the limiter. NS=4 -> grid 2048 =
// 8 blocks/CU co-resident (LDS 8x18432=147KB<=160KB, VGPR 60<=64).
// ROUND-4 LESSON: K-direct-from-global falsified (uncoalesced, 121.6 us).
// ROUND-2/6 LESSON: launch_bounds (256,N) budgets ~512/(2N) VGPR; (256,4)
// = 64 fits this body's measured 60.
// Layouts (32x32x16, verified m74/m101):
//   A: A[m = lane&31][k = (lane>>5)*8 + j]
//   B: B[k = (lane>>5)*8 + j][n = lane&31]
//   C: col(n) = lane&31, row(m) = (reg&3) + 8*(reg>>2) + 4*(lane>>5)
// ---------------------------------------------------------------------------
#define KST 72
#define VST 72

template<int NS>
__global__ __launch_bounds__(256, 4) void attn_mfma(
    const short* __restrict__ q2,   // ROWS x 512 bf16 (pre-scaled)
    const short* __restrict__ kv2,  // ROWS x 1024 bf16
    short* __restrict__ numb,       // NS x ROWS x 512 bf16 (unnormalized O)
    float* __restrict__ lbuf)       // NS x ROWS x 8 fp32
{
    __shared__ short Ks[64 * KST];
    __shared__ short Vt[64 * VST];

    constexpr int LB = (NS == 4) ? 2 : 1;   // log2(NS)
    constexpr int KT = 32 / NS;             // key tiles per block

    const int tid = threadIdx.x;
    const int w = tid >> 6;
    const int lane = tid & 63;
    const int l31 = lane & 31;
    const int h2 = lane >> 5;

    // XCD swizzle decode (h in low 3 bits -> all parts/qtiles of (b,h) on one XCD)
    const int flat = blockIdx.x;
    const int h = flat & 7;
    const int rest = flat >> 3;
    const int part = rest & (NS - 1);
    const int rest2 = rest >> LB;
    const int qtile = rest2 & 15;
    const int b = rest2 >> 4;
    const int iq0 = qtile * 128;
    const int jt0 = part * KT;

    // --- Q fragments: B operand, 4 k-steps, registers all kernel ---
    bf16x8 qr[4];
#pragma unroll
    for (int st = 0; st < 4; ++st)
        qr[st] = *(const bf16x8*)(q2 + (size_t)(b * SEQ + iq0 + w * 32 + l31) * 512
                                  + h * 64 + st * 16 + h2 * 8);

    const short* kbase = kv2 + (size_t)(b * SEQ) * 1024 + h * 64;
    const short* vbase = kbase + 512;

    float lsum = 0.f;                 // partial: query = l31, this lane's keys
    f32x16 oacc[2];                   // [dg]; col = dim, rows = queries
#pragma unroll
    for (int dg = 0; dg < 2; ++dg)
#pragma unroll
        for (int r = 0; r < 16; ++r) oacc[dg][r] = 0.f;

    // staging indices
    const int krow = tid >> 2;          // key row 0..63
    const int kc = (tid & 3) * 16;      // dim chunk (shorts)
    const int vk4 = (tid & 15) * 4;     // key base (V^T)
    const int vd4 = (tid >> 4) * 4;     // dim base 0..60

    // --- prefetch first tile of this part ---
    bf16x8 pk0, pk1;
    bf16x4 pv0, pv1, pv2, pv3;
    {
        const short* ksrc = kbase + (size_t)(jt0 * 64 + krow) * 1024 + kc;
        pk0 = *(const bf16x8*)(ksrc);
        pk1 = *(const bf16x8*)(ksrc + 8);
        const short* vs = vbase + (size_t)(jt0 * 64 + vk4) * 1024 + vd4;
        pv0 = *(const bf16x4*)(vs);
        pv1 = *(const bf16x4*)(vs + 1024);
        pv2 = *(const bf16x4*)(vs + 2048);
        pv3 = *(const bf16x4*)(vs + 3072);
    }

    for (int jt = jt0; jt < jt0 + KT; ++jt) {
        __syncthreads();
        *(bf16x8*)(&Ks[krow * KST + kc]) = pk0;
        *(bf16x8*)(&Ks[krow * KST + kc + 8]) = pk1;
        {
            bf16x4 c0_, c1_, c2_, c3_;
            c0_[0] = pv0[0]; c0_[1] = pv1[0]; c0_[2] = pv2[0]; c0_[3] = pv3[0];
            c1_[0] = pv0[1]; c1_[1] = pv1[1]; c1_[2] = pv2[1]; c1_[3] = pv3[1];
            c2_[0] = pv0[2]; c2_[1] = pv1[2]; c2_[2] = pv2[2]; c2_[3] = pv3[2];
            c3_[0] = pv0[3]; c3_[1] = pv1[3]; c3_[2] = pv2[3]; c3_[3] = pv3[3];
            *(bf16x4*)(&Vt[(vd4 + 0) * VST + vk4]) = c0_;
            *(bf16x4*)(&Vt[(vd4 + 1) * VST + vk4]) = c1_;
            *(bf16x4*)(&Vt[(vd4 + 2) * VST + vk4]) = c2_;
            *(bf16x4*)(&Vt[(vd4 + 3) * VST + vk4]) = c3_;
        }
        __syncthreads();

        // prefetch next tile
        if (jt + 1 < jt0 + KT) {
            const short* ksrc = kbase + (size_t)((jt + 1) * 64 + krow) * 1024 + kc;
            pk0 = *(const bf16x8*)(ksrc);
            pk1 = *(const bf16x8*)(ksrc + 8);
            const short* vs = vbase + (size_t)((jt + 1) * 64 + vk4) * 1024 + vd4;
            pv0 = *(const bf16x4*)(vs);
            pv1 = *(const bf16x4*)(vs + 1024);
            pv2 = *(const bf16x4*)(vs + 2048);
            pv3 = *(const bf16x4*)(vs + 3072);
        }

        // --- S^T = K Q^T (2 key-groups x 4 k-steps); P stays in registers ---
        bf16x8 pfrag[4];
#pragma unroll
        for (int kg = 0; kg < 2; ++kg) {
            f32x16 s;
#pragma unroll
            for (int r = 0; r < 16; ++r) s[r] = 0.f;
#pragma unroll
            for (int st = 0; st < 4; ++st) {
                const bf16x8 kf = *(const bf16x8*)(&Ks[(kg * 32 + l31) * KST + st * 16 + h2 * 8]);
                s = __builtin_amdgcn_mfma_f32_32x32x16_bf16(kf, qr[st], s, 0, 0, 0);
            }
            // exp2 + pack pairs: wv[2g]   = keys (8g+4*h2, 8g+1+4*h2)
            //                    wv[2g+1] = keys (8g+2+4*h2, 8g+3+4*h2)
            unsigned wv[8];
#pragma unroll
            for (int g = 0; g < 4; ++g) {
                const float p0 = __builtin_amdgcn_exp2f(s[4 * g + 0]);
                const float p1 = __builtin_amdgcn_exp2f(s[4 * g + 1]);
                const float p2 = __builtin_amdgcn_exp2f(s[4 * g + 2]);
                const float p3 = __builtin_amdgcn_exp2f(s[4 * g + 3]);
                lsum += (p0 + p1) + (p2 + p3);
                wv[2 * g]     = pack2bf(p0, p1);
                wv[2 * g + 1] = pack2bf(p2, p3);
            }
            // v_permlane32_swap_b32: lane l <-> l+32 (same query row l31).
            // swap(wv0,wv2) -> A-words 0,2 ; swap(wv1,wv3) -> A-words 1,3
#pragma unroll
            for (int q = 0; q < 2; ++q) {
                unsigned a0 = wv[4 * q + 0], b0 = wv[4 * q + 2];
                unsigned a1 = wv[4 * q + 1], b1 = wv[4 * q + 3];
                asm volatile("v_permlane32_swap_b32 %0, %1" : "+v"(a0), "+v"(b0));
                asm volatile("v_permlane32_swap_b32 %0, %1" : "+v"(a1), "+v"(b1));
                union { unsigned u[4]; bf16x8 v; } f;
                f.u[0] = a0; f.u[1] = a1; f.u[2] = b0; f.u[3] = b1;
                pfrag[kg * 2 + q] = f.v;
            }
        }

        // --- O += P V (4 k-steps x 2 dim-groups) ---
#pragma unroll
        for (int st = 0; st < 4; ++st) {
            const bf16x8 pf = pfrag[st];
#pragma unroll
            for (int dg = 0; dg < 2; ++dg) {
                const bf16x8 vf = *(const bf16x8*)(&Vt[(dg * 32 + l31) * VST + st * 16 + h2 * 8]);
                oacc[dg] = __builtin_amdgcn_mfma_f32_32x32x16_bf16(pf, vf, oacc[dg], 0, 0, 0);
            }
        }
    }

    // --- epilogue: combine h2 halves of lsum; store partial l and O ---
    lsum += __shfl_xor(lsum, 32);     // all 64 keys for query = w*32 + l31
    short* nb = numb + (size_t)part * ROWS * 512;
    float* lb = lbuf + (size_t)part * ROWS * 8;
    if (lane < 32)
        lb[(size_t)(b * SEQ + iq0 + w * 32 + l31) * 8 + h] = lsum;
#pragma unroll
    for (int dg = 0; dg < 2; ++dg)
#pragma unroll
        for (int r = 0; r < 16; ++r) {
            const int qrow = w * 32 + (r & 3) + 8 * (r >> 2) + 4 * h2;
            nb[(size_t)(b * SEQ + iq0 + qrow) * 512 + h * 64 + dg * 32 + l31] =
                f2bf(oacc[dg][r]);
        }
}

// ---------------------------------------------------------------------------
extern "C" void kernel_launch(void* const* d_in, const int* in_sizes, int n_in,
                              void* d_out, int out_size, void* d_ws, size_t ws_size,
                              hipStream_t stream) {
    const float* x   = (const float*)d_in[0];  // (4,2048,256)
    const float* ctx = (const float*)d_in[1];  // (4,2048,256)
    const float* Wq  = (const float*)d_in[2];  // (512,256)
    const float* bq  = (const float*)d_in[3];
    const float* Wkv = (const float*)d_in[4];  // (1024,256)
    const float* bkv = (const float*)d_in[5];
    const float* Wo  = (const float*)d_in[6];  // (256,512)
    const float* bo  = (const float*)d_in[7];
    float* out = (float*)d_out;                // (4,2048,256) fp32

    short* xb   = (short*)d_ws;                         // ROWS*256
    short* cb   = xb + (size_t)ROWS * 256;              // ROWS*256
    short* wqb  = cb + (size_t)ROWS * 256;              // 131072
    short* wkvb = wqb + 131072;                         // 262144
    short* wob  = wkvb + 262144;                        // 131072
    short* q2b  = wob + 131072;                         // ROWS*512
    short* kv2b = q2b + (size_t)ROWS * 512;             // ROWS*1024
    short* numb = kv2b + (size_t)ROWS * 1024;           // NS*ROWS*512

    const float qscale = 0.125f * 1.44269504088896f;   // softmax scale + log2e

    cvt_all<<<4608, 256, 0, stream>>>(x, ctx, Wq, Wkv, Wo,
                                      xb, cb, wqb, wkvb, wob);
    // merged q+kv projection, 128x128 tiles, pure bf16 (768 blocks = 3/CU)
    proj2<<<768, 256, 0, stream>>>(xb, wqb, bq, cb, wkvb, bkv,
                                   q2b, kv2b, qscale);

    // split-K factor: 4 if workspace allows (grid 2048 = 8 blocks/CU), else
    // the round-1 2-way layout (grid 1024 = 4 blocks/CU, measured 55.4 us).
    const size_t head_bytes = (size_t)((char*)numb - (char*)d_ws);
    const size_t need4 = head_bytes + (size_t)4 * ROWS * 512 * 2
                                    + (size_t)4 * ROWS * 8 * 4;
    if (ws_size >= need4) {
        float* lbuf = (float*)(numb + (size_t)4 * ROWS * 512); // 4*ROWS*8 fp32
        attn_mfma<4><<<NB * NHEADS * (SEQ / 128) * 4, 256, 0, stream>>>(
            q2b, kv2b, numb, lbuf);
        gemm64_ocomb<4><<<dim3(256 / 64, ROWS / 64), 256, 0, stream>>>(
            numb, lbuf, wob, bo, out);
    } else {
        float* lbuf = (float*)(numb + (size_t)2 * ROWS * 512); // 2*ROWS*8 fp32
        attn_mfma<2><<<NB * NHEADS * (SEQ / 128) * 2, 256, 0, stream>>>(
            q2b, kv2b, numb, lbuf);
        gemm64_ocomb<2><<<dim3(256 / 64, ROWS / 64), 256, 0, stream>>>(
            numb, lbuf, wob, bo, out);
    }
}

// Round 10
// 159.568 us; speedup vs baseline: 1.0419x; 1.0306x over previous
//
#include <hip/hip_runtime.h>
#include <hip/hip_bf16.h>

#define NB 4
#define SEQ 2048
#define NHEADS 8
#define ROWS (NB * SEQ)

typedef __attribute__((ext_vector_type(8))) short bf16x8;
typedef __attribute__((ext_vector_type(4))) short bf16x4;
typedef __attribute__((ext_vector_type(4))) float f32x4;
typedef __attribute__((ext_vector_type(16))) float f32x16;

__device__ inline short f2bf(float x) {
    union { float f; unsigned u; } v; v.f = x;
    unsigned r = v.u + 0x7FFF + ((v.u >> 16) & 1);
    return (short)(r >> 16);
}

__device__ inline unsigned pack2bf(float a, float b) {
    __hip_bfloat162 h = __float22bfloat162_rn(make_float2(a, b));
    unsigned u; __builtin_memcpy(&u, &h, 4);
    return u;
}

// combine two packed-bf16 pairs from the two K-halves and scale: bf16 out
__device__ inline unsigned comb2(unsigned w1, unsigned w2, float inv) {
    union { unsigned v; float f; } a, b, c, d;
    a.v = w1 << 16;          b.v = w2 << 16;
    c.v = w1 & 0xffff0000u;  d.v = w2 & 0xffff0000u;
    return pack2bf((a.f + b.f) * inv, (c.f + d.f) * inv);
}

// ---------------------------------------------------------------------------
// Fused fp32 -> bf16 cast for all 5 inputs (one launch). Unit = 4 elements.
// x 524288 | ctx 524288 | Wq 32768 | Wkv 65536 | Wo 32768 -> 1179648 units.
// ---------------------------------------------------------------------------
__global__ __launch_bounds__(256) void cvt_all(
    const float* __restrict__ x, const float* __restrict__ ctx,
    const float* __restrict__ wq, const float* __restrict__ wkv,
    const float* __restrict__ wo,
    short* __restrict__ xb, short* __restrict__ cb, short* __restrict__ wqb,
    short* __restrict__ wkvb, short* __restrict__ wob)
{
    const int i = blockIdx.x * 256 + threadIdx.x;
    const float* src; short* dst; int off;
    if (i < 524288)       { src = x;   dst = xb;   off = i; }
    else if (i < 1048576) { src = ctx; dst = cb;   off = i - 524288; }
    else if (i < 1081344) { src = wq;  dst = wqb;  off = i - 1048576; }
    else if (i < 1146880) { src = wkv; dst = wkvb; off = i - 1081344; }
    else                  { src = wo;  dst = wob;  off = i - 1146880; }
    const float4 v = ((const float4*)src)[off];
    uint2 o2;
    o2.x = pack2bf(v.x, v.y);
    o2.y = pack2bf(v.z, v.w);
    *(uint2*)(dst + (size_t)off * 4) = o2;
}

// ---------------------------------------------------------------------------
// Merged q+kv projection, pure bf16, 128x128 tiles, BK=64, K=256.
// Grid 768: bid<512 -> kv tile (col=bid&7, row=bid>>3, Ccols=1024);
//           bid>=512 -> q tile (u=bid-512, col=u&3, row=u>>2, Ccols=512,
//           output pre-scaled by qscale = 0.125*log2e).
// 4 waves in 2x2, each 64x64. XOR-swizzled unpadded LDS; register prefetch.
// ROUND-10 FIX: launch_bounds (256,3) caps VGPR at ~84 (measured decode:
// cap ~= 512/(2N)); live set here is ~130-140 (acc 64 + pab/pwb 32 +
// af/bfv 32 + addr) -> the kernel has been SPILLING all session (same
// signature that cost attn 3x in round 2, but proj2 never surfaced in
// top-5 so it went unchecked). (256,2) -> 128-VGPR cap; HW residency at
// ~128 VGPR is still 4 waves/SIMD, and grid 768 (=3 blocks/CU) was the
// actual limiter, so occupancy is unchanged -- only the spill goes away.
// ---------------------------------------------------------------------------
__global__ __launch_bounds__(256, 2) void proj2(
    const short* __restrict__ xb, const short* __restrict__ wqb,
    const float* __restrict__ bq,
    const short* __restrict__ cb, const short* __restrict__ wkvb,
    const float* __restrict__ bkv,
    short* __restrict__ q2b, short* __restrict__ kv2b, float qscale)
{
    __shared__ short As[128 * 64];
    __shared__ short Ws[128 * 64];
    const int tid = threadIdx.x;
    const int bid = blockIdx.x;
    const int w = tid >> 6, lane = tid & 63, low = lane & 15, quad = lane >> 4;
    const int wm = w >> 1, wn = w & 1;
    const int K = 256;

    const short* A; const short* W; const float* bias;
    short* outp; int Ccols; float scale; int rM0, c0;
    if (bid < 512) {
        A = cb; W = wkvb; bias = bkv; outp = kv2b; Ccols = 1024; scale = 1.0f;
        c0 = (bid & 7) * 128; rM0 = (bid >> 3) * 128;
    } else {
        const int u = bid - 512;
        A = xb; W = wqb; bias = bq; outp = q2b; Ccols = 512; scale = qscale;
        c0 = (u & 3) * 128; rM0 = (u >> 2) * 128;
    }

    const int srow = tid >> 3, sj = tid & 7;

    f32x4 acc[4][4];
#pragma unroll
    for (int mt = 0; mt < 4; ++mt)
#pragma unroll
        for (int nt = 0; nt < 4; ++nt) acc[mt][nt] = (f32x4){0.f, 0.f, 0.f, 0.f};

    bf16x8 pab[4], pwb[4];
#pragma unroll
    for (int c = 0; c < 4; ++c) {
        const int row = c * 32 + srow;
        pab[c] = *(const bf16x8*)(A + (size_t)(rM0 + row) * K + sj * 8);
        pwb[c] = *(const bf16x8*)(W + (size_t)(c0 + row) * K + sj * 8);
    }

    int k0 = 0;
    for (;;) {
        __syncthreads();
#pragma unroll
        for (int c = 0; c < 4; ++c) {
            const int row = c * 32 + srow;
            const int pc = sj ^ (row & 7);
            *(bf16x8*)(&As[row * 64 + pc * 8]) = pab[c];
            *(bf16x8*)(&Ws[row * 64 + pc * 8]) = pwb[c];
        }
        __syncthreads();
        const int kn = k0 + 64;
        if (kn < K) {
#pragma unroll
            for (int c = 0; c < 4; ++c) {
                const int row = c * 32 + srow;
                pab[c] = *(const bf16x8*)(A + (size_t)(rM0 + row) * K + kn + sj * 8);
                pwb[c] = *(const bf16x8*)(W + (size_t)(c0 + row) * K + kn + sj * 8);
            }
        }
#pragma unroll
        for (int kh = 0; kh < 2; ++kh) {
            bf16x8 af[4], bfv[4];
#pragma unroll
            for (int t = 0; t < 4; ++t) {
                const int ra = wm * 64 + t * 16 + low;
                af[t] = *(const bf16x8*)(&As[ra * 64 + ((kh * 4 + quad) ^ (ra & 7)) * 8]);
                const int rb = wn * 64 + t * 16 + low;
                bfv[t] = *(const bf16x8*)(&Ws[rb * 64 + ((kh * 4 + quad) ^ (rb & 7)) * 8]);
            }
#pragma unroll
            for (int mt = 0; mt < 4; ++mt)
#pragma unroll
                for (int nt = 0; nt < 4; ++nt)
                    acc[mt][nt] = __builtin_amdgcn_mfma_f32_16x16x32_bf16(af[mt], bfv[nt], acc[mt][nt], 0, 0, 0);
        }
        k0 = kn;
        if (k0 >= K) break;
    }

#pragma unroll
    for (int nt = 0; nt < 4; ++nt) {
        const int col = c0 + wn * 64 + nt * 16 + low;
        const float bv = bias[col];
#pragma unroll
        for (int mt = 0; mt < 4; ++mt) {
            const size_t rbase = (size_t)(rM0 + wm * 64 + mt * 16 + quad * 4);
#pragma unroll
            for (int r = 0; r < 4; ++r)
                outp[(rbase + r) * Ccols + col] = f2bf((acc[mt][nt][r] + bv) * scale);
        }
    }
}

// ---------------------------------------------------------------------------
// o-GEMM with fused split-K combine, all-bf16 staging (Wo pre-cast):
// A[r][e] = (num1[r][e]+num2[r][e]) / (l1[r][h]+l2[r][h]), h = e/64.
// ---------------------------------------------------------------------------
__global__ __launch_bounds__(256) void gemm64_ocomb(
    const short* __restrict__ num, const float* __restrict__ lbuf,
    const short* __restrict__ W, const float* __restrict__ bias,
    float* __restrict__ out)
{
    const int K = 512, Ccols = 256;
    const size_t NHALF = (size_t)ROWS * 512;
    const int R8 = ROWS * 8;
    __shared__ short As[64 * 64];
    __shared__ short Ws[64 * 64];
    const int tid = threadIdx.x;
    const int w = tid >> 6, lane = tid & 63, low = lane & 15, quad = lane >> 4;
    const int wm = w >> 1, wn = w & 1;
    const int r0 = blockIdx.y * 64, c0 = blockIdx.x * 64;
    const int srow = tid >> 2;
    const int sc = (tid & 3) * 2;

    f32x4 acc[2][2];
#pragma unroll
    for (int mt = 0; mt < 2; ++mt)
#pragma unroll
        for (int nt = 0; nt < 2; ++nt) acc[mt][nt] = (f32x4){0.f, 0.f, 0.f, 0.f};

    uint4 pa1[2], pa2[2];
    float pinv;
    bf16x8 pwb[2];

    auto loadA = [&](int k0) {
        const int hh = k0 >> 6;
        const int row = r0 + srow;
        pinv = lbuf[row * 8 + hh] + lbuf[R8 + row * 8 + hh];
        const short* p1 = num + (size_t)row * 512 + k0 + sc * 8;
        pa1[0] = ((const uint4*)p1)[0];
        pa1[1] = ((const uint4*)p1)[1];
        const short* p2 = p1 + NHALF;
        pa2[0] = ((const uint4*)p2)[0];
        pa2[1] = ((const uint4*)p2)[1];
    };
    auto loadW = [&](int k0) {
        const short* p = W + (size_t)(c0 + srow) * K + k0 + sc * 8;
        pwb[0] = ((const bf16x8*)p)[0];
        pwb[1] = ((const bf16x8*)p)[1];
    };

    loadA(0); loadW(0);

    int k0 = 0;
    for (;;) {
        __syncthreads();
        {
            const float inv = 1.f / pinv;
#pragma unroll
            for (int c = 0; c < 2; ++c) {
                const int pc = (sc + c) ^ (srow & 7);
                union { unsigned u[4]; bf16x8 v; } r;
                r.u[0] = comb2(pa1[c].x, pa2[c].x, inv);
                r.u[1] = comb2(pa1[c].y, pa2[c].y, inv);
                r.u[2] = comb2(pa1[c].z, pa2[c].z, inv);
                r.u[3] = comb2(pa1[c].w, pa2[c].w, inv);
                *(bf16x8*)(&As[srow * 64 + pc * 8]) = r.v;
                *(bf16x8*)(&Ws[srow * 64 + pc * 8]) = pwb[c];
            }
        }
        __syncthreads();
        const int kn = k0 + 64;
        if (kn < K) { loadA(kn); loadW(kn); }
#pragma unroll
        for (int kh = 0; kh < 2; ++kh) {
            bf16x8 af[2], bfv[2];
#pragma unroll
            for (int t = 0; t < 2; ++t) {
                const int ra = wm * 32 + t * 16 + low;
                af[t] = *(const bf16x8*)(&As[ra * 64 + ((kh * 4 + quad) ^ (ra & 7)) * 8]);
                const int rb = wn * 32 + t * 16 + low;
                bfv[t] = *(const bf16x8*)(&Ws[rb * 64 + ((kh * 4 + quad) ^ (rb & 7)) * 8]);
            }
#pragma unroll
            for (int mt = 0; mt < 2; ++mt)
#pragma unroll
                for (int nt = 0; nt < 2; ++nt)
                    acc[mt][nt] = __builtin_amdgcn_mfma_f32_16x16x32_bf16(af[mt], bfv[nt], acc[mt][nt], 0, 0, 0);
        }
        k0 = kn;
        if (k0 >= K) break;
    }

#pragma unroll
    for (int nt = 0; nt < 2; ++nt) {
        const int col = c0 + wn * 32 + nt * 16 + low;
        const float bv = bias[col];
#pragma unroll
        for (int mt = 0; mt < 2; ++mt) {
            const size_t rbase = (size_t)(r0 + wm * 32 + mt * 16 + quad * 4);
#pragma unroll
            for (int r = 0; r < 4; ++r)
                out[(rbase + r) * Ccols + col] = acc[mt][nt][r] + bv;
        }
    }
}

// ---------------------------------------------------------------------------
// MFMA flash attention (32x32x16): split-K x2 over keys, XCD-swizzled 1-D
// grid, reads pre-projected/pre-scaled q2. Round-1 structure exactly
// (single-buffered Ks/Vt, 2 barriers/iter, coalesced staging, P in regs via
// cvt_pk + v_permlane32_swap_b32): measured 55.4 us / VGPR 60 / 18KB LDS.
// ATTENTION PLATEAU (rounds 1-9): three clean variants converge --
//   round-1 (4 blk/CU, 2 barriers)       55.4 us  MfmaUtil 24.7 VALU 41.5
//   dbuf 1-barrier (4 blk/CU, 36KB LDS)  70.2 us  (occupancy 30->22, lost)
//   split-K x4 (8 blk/CU)                57.5 us  (occupancy +3% only, null)
// => throughput-bound on the VALU(exp2/pack/permlane)+LDS mix, not
// occupancy- or barrier-bound. Keep this form.
// ROUND-4: K-direct-from-global falsified (uncoalesced, 121.6 us).
// ROUND-2/6: launch_bounds (256,N) caps VGPR ~512/(2N); (256,4)=64 fits
// this body's measured 60.
// Layouts (32x32x16, verified m74/m101):
//   A: A[m = lane&31][k = (lane>>5)*8 + j]
//   B: B[k = (lane>>5)*8 + j][n = lane&31]
//   C: col(n) = lane&31, row(m) = (reg&3) + 8*(reg>>2) + 4*(lane>>5)
// ---------------------------------------------------------------------------
#define KST 72
#define VST 72
#define PST 72

__global__ __launch_bounds__(256, 4) void attn_mfma(
    const short* __restrict__ q2,   // ROWS x 512 bf16 (pre-scaled)
    const short* __restrict__ kv2,  // ROWS x 1024 bf16
    short* __restrict__ numb,       // 2 x ROWS x 512 bf16 (unnormalized O)
    float* __restrict__ lbuf)       // 2 x ROWS x 8 fp32
{
    __shared__ short Ks[64 * KST];
    __shared__ short Vt[64 * VST];

    const int tid = threadIdx.x;
    const int w = tid >> 6;
    const int lane = tid & 63;
    const int l31 = lane & 31;
    const int h2 = lane >> 5;

    // XCD swizzle decode
    const int flat = blockIdx.x;
    const int h = flat & 7;
    const int rest = flat >> 3;
    const int half = rest & 1;
    const int rest2 = rest >> 1;
    const int qtile = rest2 & 15;
    const int b = rest2 >> 4;
    const int iq0 = qtile * 128;
    const int jt0 = half * 16;

    // --- Q fragments: B operand, 4 k-steps, registers all kernel ---
    bf16x8 qr[4];
#pragma unroll
    for (int st = 0; st < 4; ++st)
        qr[st] = *(const bf16x8*)(q2 + (size_t)(b * SEQ + iq0 + w * 32 + l31) * 512
                                  + h * 64 + st * 16 + h2 * 8);

    const short* kbase = kv2 + (size_t)(b * SEQ) * 1024 + h * 64;
    const short* vbase = kbase + 512;

    float lsum = 0.f;                 // partial: query = l31, this lane's keys
    f32x16 oacc[2];                   // [dg]; col = dim, rows = queries
#pragma unroll
    for (int dg = 0; dg < 2; ++dg)
#pragma unroll
        for (int r = 0; r < 16; ++r) oacc[dg][r] = 0.f;

    // staging indices
    const int krow = tid >> 2;          // key row 0..63
    const int kc = (tid & 3) * 16;      // dim chunk (shorts)
    const int vk4 = (tid & 15) * 4;     // key base (V^T)
    const int vd4 = (tid >> 4) * 4;     // dim base 0..60

    // --- prefetch first tile of this half ---
    bf16x8 pk0, pk1;
    bf16x4 pv0, pv1, pv2, pv3;
    {
        const short* ksrc = kbase + (size_t)(jt0 * 64 + krow) * 1024 + kc;
        pk0 = *(const bf16x8*)(ksrc);
        pk1 = *(const bf16x8*)(ksrc + 8);
        const short* vs = vbase + (size_t)(jt0 * 64 + vk4) * 1024 + vd4;
        pv0 = *(const bf16x4*)(vs);
        pv1 = *(const bf16x4*)(vs + 1024);
        pv2 = *(const bf16x4*)(vs + 2048);
        pv3 = *(const bf16x4*)(vs + 3072);
    }

    for (int jt = jt0; jt < jt0 + 16; ++jt) {
        __syncthreads();
        *(bf16x8*)(&Ks[krow * KST + kc]) = pk0;
        *(bf16x8*)(&Ks[krow * KST + kc + 8]) = pk1;
        {
            bf16x4 c0_, c1_, c2_, c3_;
            c0_[0] = pv0[0]; c0_[1] = pv1[0]; c0_[2] = pv2[0]; c0_[3] = pv3[0];
            c1_[0] = pv0[1]; c1_[1] = pv1[1]; c1_[2] = pv2[1]; c1_[3] = pv3[1];
            c2_[0] = pv0[2]; c2_[1] = pv1[2]; c2_[2] = pv2[2]; c2_[3] = pv3[2];
            c3_[0] = pv0[3]; c3_[1] = pv1[3]; c3_[2] = pv2[3]; c3_[3] = pv3[3];
            *(bf16x4*)(&Vt[(vd4 + 0) * VST + vk4]) = c0_;
            *(bf16x4*)(&Vt[(vd4 + 1) * VST + vk4]) = c1_;
            *(bf16x4*)(&Vt[(vd4 + 2) * VST + vk4]) = c2_;
            *(bf16x4*)(&Vt[(vd4 + 3) * VST + vk4]) = c3_;
        }
        __syncthreads();

        // prefetch next tile
        if (jt + 1 < jt0 + 16) {
            const short* ksrc = kbase + (size_t)((jt + 1) * 64 + krow) * 1024 + kc;
            pk0 = *(const bf16x8*)(ksrc);
            pk1 = *(const bf16x8*)(ksrc + 8);
            const short* vs = vbase + (size_t)((jt + 1) * 64 + vk4) * 1024 + vd4;
            pv0 = *(const bf16x4*)(vs);
            pv1 = *(const bf16x4*)(vs + 1024);
            pv2 = *(const bf16x4*)(vs + 2048);
            pv3 = *(const bf16x4*)(vs + 3072);
        }

        // --- S^T = K Q^T (2 key-groups x 4 k-steps); P stays in registers ---
        bf16x8 pfrag[4];
#pragma unroll
        for (int kg = 0; kg < 2; ++kg) {
            f32x16 s;
#pragma unroll
            for (int r = 0; r < 16; ++r) s[r] = 0.f;
#pragma unroll
            for (int st = 0; st < 4; ++st) {
                const bf16x8 kf = *(const bf16x8*)(&Ks[(kg * 32 + l31) * KST + st * 16 + h2 * 8]);
                s = __builtin_amdgcn_mfma_f32_32x32x16_bf16(kf, qr[st], s, 0, 0, 0);
            }
            // exp2 + pack pairs: wv[2g]   = keys (8g+4*h2, 8g+1+4*h2)
            //                    wv[2g+1] = keys (8g+2+4*h2, 8g+3+4*h2)
            unsigned wv[8];
#pragma unroll
            for (int g = 0; g < 4; ++g) {
                const float p0 = __builtin_amdgcn_exp2f(s[4 * g + 0]);
                const float p1 = __builtin_amdgcn_exp2f(s[4 * g + 1]);
                const float p2 = __builtin_amdgcn_exp2f(s[4 * g + 2]);
                const float p3 = __builtin_amdgcn_exp2f(s[4 * g + 3]);
                lsum += (p0 + p1) + (p2 + p3);
                wv[2 * g]     = pack2bf(p0, p1);
                wv[2 * g + 1] = pack2bf(p2, p3);
            }
            // v_permlane32_swap_b32: lane l <-> l+32 (same query row l31).
            // swap(wv0,wv2) -> A-words 0,2 ; swap(wv1,wv3) -> A-words 1,3
#pragma unroll
            for (int q = 0; q < 2; ++q) {
                unsigned a0 = wv[4 * q + 0], b0 = wv[4 * q + 2];
                unsigned a1 = wv[4 * q + 1], b1 = wv[4 * q + 3];
                asm volatile("v_permlane32_swap_b32 %0, %1" : "+v"(a0), "+v"(b0));
                asm volatile("v_permlane32_swap_b32 %0, %1" : "+v"(a1), "+v"(b1));
                union { unsigned u[4]; bf16x8 v; } f;
                f.u[0] = a0; f.u[1] = a1; f.u[2] = b0; f.u[3] = b1;
                pfrag[kg * 2 + q] = f.v;
            }
        }

        // --- O += P V (4 k-steps x 2 dim-groups), P from registers ---
#pragma unroll
        for (int st = 0; st < 4; ++st) {
            const bf16x8 pf = pfrag[st];
#pragma unroll
            for (int dg = 0; dg < 2; ++dg) {
                const bf16x8 vf = *(const bf16x8*)(&Vt[(dg * 32 + l31) * VST + st * 16 + h2 * 8]);
                oacc[dg] = __builtin_amdgcn_mfma_f32_32x32x16_bf16(pf, vf, oacc[dg], 0, 0, 0);
            }
        }
    }

    // --- epilogue: combine h2 halves of lsum; store partial l and O ---
    lsum += __shfl_xor(lsum, 32);     // all 64 keys for query = w*32 + l31
    short* nb = numb + (size_t)half * ROWS * 512;
    float* lb = lbuf + (size_t)half * ROWS * 8;
    if (lane < 32)
        lb[(size_t)(b * SEQ + iq0 + w * 32 + l31) * 8 + h] = lsum;
#pragma unroll
    for (int dg = 0; dg < 2; ++dg)
#pragma unroll
        for (int r = 0; r < 16; ++r) {
            const int qrow = w * 32 + (r & 3) + 8 * (r >> 2) + 4 * h2;
            nb[(size_t)(b * SEQ + iq0 + qrow) * 512 + h * 64 + dg * 32 + l31] =
                f2bf(oacc[dg][r]);
        }
}

// ---------------------------------------------------------------------------
extern "C" void kernel_launch(void* const* d_in, const int* in_sizes, int n_in,
                              void* d_out, int out_size, void* d_ws, size_t ws_size,
                              hipStream_t stream) {
    const float* x   = (const float*)d_in[0];  // (4,2048,256)
    const float* ctx = (const float*)d_in[1];  // (4,2048,256)
    const float* Wq  = (const float*)d_in[2];  // (512,256)
    const float* bq  = (const float*)d_in[3];
    const float* Wkv = (const float*)d_in[4];  // (1024,256)
    const float* bkv = (const float*)d_in[5];
    const float* Wo  = (const float*)d_in[6];  // (256,512)
    const float* bo  = (const float*)d_in[7];
    float* out = (float*)d_out;                // (4,2048,256) fp32

    short* xb   = (short*)d_ws;                         // ROWS*256
    short* cb   = xb + (size_t)ROWS * 256;              // ROWS*256
    short* wqb  = cb + (size_t)ROWS * 256;              // 131072
    short* wkvb = wqb + 131072;                         // 262144
    short* wob  = wkvb + 262144;                        // 131072
    short* q2b  = wob + 131072;                         // ROWS*512
    short* kv2b = q2b + (size_t)ROWS * 512;             // ROWS*1024
    short* numb = kv2b + (size_t)ROWS * 1024;           // 2*ROWS*512
    float* lbuf = (float*)(numb + (size_t)2 * ROWS * 512); // 2*ROWS*8

    const float qscale = 0.125f * 1.44269504088896f;   // softmax scale + log2e

    cvt_all<<<4608, 256, 0, stream>>>(x, ctx, Wq, Wkv, Wo,
                                      xb, cb, wqb, wkvb, wob);
    // merged q+kv projection, 128x128 tiles, pure bf16 (768 blocks = 3/CU)
    proj2<<<768, 256, 0, stream>>>(xb, wqb, bq, cb, wkvb, bkv,
                                   q2b, kv2b, qscale);
    // attention, split-K x2, 32x32x16 MFMA, XCD-swizzled 1-D grid (1024 blocks)
    attn_mfma<<<NB * NHEADS * (SEQ / 128) * 2, 256, 0, stream>>>(
        q2b, kv2b, numb, lbuf);
    // out = combine(num1,num2)/(l1+l2) * Wo^T + bo (bf16 Wo)
    gemm64_ocomb<<<dim3(256 / 64, ROWS / 64), 256, 0, stream>>>(
        numb, lbuf, wob, bo, out);
}

// Round 11
// 151.780 us; speedup vs baseline: 1.0954x; 1.0513x over previous
//
#include <hip/hip_runtime.h>
#include <hip/hip_bf16.h>

#define NB 4
#define SEQ 2048
#define NHEADS 8
#define ROWS (NB * SEQ)

typedef __attribute__((ext_vector_type(8))) short bf16x8;
typedef __attribute__((ext_vector_type(4))) short bf16x4;
typedef __attribute__((ext_vector_type(4))) float f32x4;
typedef __attribute__((ext_vector_type(16))) float f32x16;

__device__ inline short f2bf(float x) {
    union { float f; unsigned u; } v; v.f = x;
    unsigned r = v.u + 0x7FFF + ((v.u >> 16) & 1);
    return (short)(r >> 16);
}

__device__ inline unsigned pack2bf(float a, float b) {
    __hip_bfloat162 h = __float22bfloat162_rn(make_float2(a, b));
    unsigned u; __builtin_memcpy(&u, &h, 4);
    return u;
}

// combine two packed-bf16 pairs from the two K-halves and scale: bf16 out
__device__ inline unsigned comb2(unsigned w1, unsigned w2, float inv) {
    union { unsigned v; float f; } a, b, c, d;
    a.v = w1 << 16;          b.v = w2 << 16;
    c.v = w1 & 0xffff0000u;  d.v = w2 & 0xffff0000u;
    return pack2bf((a.f + b.f) * inv, (c.f + d.f) * inv);
}

// ---------------------------------------------------------------------------
// Fused fp32 -> bf16 cast for all 5 inputs (one launch). Unit = 4 elements.
// x 524288 | ctx 524288 | Wq 32768 | Wkv 65536 | Wo 32768 -> 1179648 units.
// ---------------------------------------------------------------------------
__global__ __launch_bounds__(256) void cvt_all(
    const float* __restrict__ x, const float* __restrict__ ctx,
    const float* __restrict__ wq, const float* __restrict__ wkv,
    const float* __restrict__ wo,
    short* __restrict__ xb, short* __restrict__ cb, short* __restrict__ wqb,
    short* __restrict__ wkvb, short* __restrict__ wob)
{
    const int i = blockIdx.x * 256 + threadIdx.x;
    const float* src; short* dst; int off;
    if (i < 524288)       { src = x;   dst = xb;   off = i; }
    else if (i < 1048576) { src = ctx; dst = cb;   off = i - 524288; }
    else if (i < 1081344) { src = wq;  dst = wqb;  off = i - 1048576; }
    else if (i < 1146880) { src = wkv; dst = wkvb; off = i - 1081344; }
    else                  { src = wo;  dst = wob;  off = i - 1146880; }
    const float4 v = ((const float4*)src)[off];
    uint2 o2;
    o2.x = pack2bf(v.x, v.y);
    o2.y = pack2bf(v.z, v.w);
    *(uint2*)(dst + (size_t)off * 4) = o2;
}

// ---------------------------------------------------------------------------
// Merged q+kv projection, pure bf16, 128x128 tiles, BK=64, K=256.
// Grid 768: bid<512 -> kv tile (col=bid&7, row=bid>>3, Ccols=1024);
//           bid>=512 -> q tile (u=bid-512, col=u&3, row=u>>2, Ccols=512,
//           output pre-scaled by qscale = 0.125*log2e).
// 4 waves in 2x2, each 64x64. XOR-swizzled unpadded LDS; register prefetch.
// ROUND-10 LESSON: VGPR_Count = 84 at BOTH (256,3) and (256,2) -> 84 is the
// natural allocation, no spill (FETCH/WRITE match legit traffic). The
// proj2-spill theory is falsified; kept at round-1 baseline form.
// ---------------------------------------------------------------------------
__global__ __launch_bounds__(256, 3) void proj2(
    const short* __restrict__ xb, const short* __restrict__ wqb,
    const float* __restrict__ bq,
    const short* __restrict__ cb, const short* __restrict__ wkvb,
    const float* __restrict__ bkv,
    short* __restrict__ q2b, short* __restrict__ kv2b, float qscale)
{
    __shared__ short As[128 * 64];
    __shared__ short Ws[128 * 64];
    const int tid = threadIdx.x;
    const int bid = blockIdx.x;
    const int w = tid >> 6, lane = tid & 63, low = lane & 15, quad = lane >> 4;
    const int wm = w >> 1, wn = w & 1;
    const int K = 256;

    const short* A; const short* W; const float* bias;
    short* outp; int Ccols; float scale; int rM0, c0;
    if (bid < 512) {
        A = cb; W = wkvb; bias = bkv; outp = kv2b; Ccols = 1024; scale = 1.0f;
        c0 = (bid & 7) * 128; rM0 = (bid >> 3) * 128;
    } else {
        const int u = bid - 512;
        A = xb; W = wqb; bias = bq; outp = q2b; Ccols = 512; scale = qscale;
        c0 = (u & 3) * 128; rM0 = (u >> 2) * 128;
    }

    const int srow = tid >> 3, sj = tid & 7;

    f32x4 acc[4][4];
#pragma unroll
    for (int mt = 0; mt < 4; ++mt)
#pragma unroll
        for (int nt = 0; nt < 4; ++nt) acc[mt][nt] = (f32x4){0.f, 0.f, 0.f, 0.f};

    bf16x8 pab[4], pwb[4];
#pragma unroll
    for (int c = 0; c < 4; ++c) {
        const int row = c * 32 + srow;
        pab[c] = *(const bf16x8*)(A + (size_t)(rM0 + row) * K + sj * 8);
        pwb[c] = *(const bf16x8*)(W + (size_t)(c0 + row) * K + sj * 8);
    }

    int k0 = 0;
    for (;;) {
        __syncthreads();
#pragma unroll
        for (int c = 0; c < 4; ++c) {
            const int row = c * 32 + srow;
            const int pc = sj ^ (row & 7);
            *(bf16x8*)(&As[row * 64 + pc * 8]) = pab[c];
            *(bf16x8*)(&Ws[row * 64 + pc * 8]) = pwb[c];
        }
        __syncthreads();
        const int kn = k0 + 64;
        if (kn < K) {
#pragma unroll
            for (int c = 0; c < 4; ++c) {
                const int row = c * 32 + srow;
                pab[c] = *(const bf16x8*)(A + (size_t)(rM0 + row) * K + kn + sj * 8);
                pwb[c] = *(const bf16x8*)(W + (size_t)(c0 + row) * K + kn + sj * 8);
            }
        }
#pragma unroll
        for (int kh = 0; kh < 2; ++kh) {
            bf16x8 af[4], bfv[4];
#pragma unroll
            for (int t = 0; t < 4; ++t) {
                const int ra = wm * 64 + t * 16 + low;
                af[t] = *(const bf16x8*)(&As[ra * 64 + ((kh * 4 + quad) ^ (ra & 7)) * 8]);
                const int rb = wn * 64 + t * 16 + low;
                bfv[t] = *(const bf16x8*)(&Ws[rb * 64 + ((kh * 4 + quad) ^ (rb & 7)) * 8]);
            }
#pragma unroll
            for (int mt = 0; mt < 4; ++mt)
#pragma unroll
                for (int nt = 0; nt < 4; ++nt)
                    acc[mt][nt] = __builtin_amdgcn_mfma_f32_16x16x32_bf16(af[mt], bfv[nt], acc[mt][nt], 0, 0, 0);
        }
        k0 = kn;
        if (k0 >= K) break;
    }

#pragma unroll
    for (int nt = 0; nt < 4; ++nt) {
        const int col = c0 + wn * 64 + nt * 16 + low;
        const float bv = bias[col];
#pragma unroll
        for (int mt = 0; mt < 4; ++mt) {
            const size_t rbase = (size_t)(rM0 + wm * 64 + mt * 16 + quad * 4);
#pragma unroll
            for (int r = 0; r < 4; ++r)
                outp[(rbase + r) * Ccols + col] = f2bf((acc[mt][nt][r] + bv) * scale);
        }
    }
}

// ---------------------------------------------------------------------------
// o-GEMM with fused split-K combine, all-bf16 staging (Wo pre-cast):
// A[r][e] = (num1[r][e]+num2[r][e]) / (l1[r][h]+l2[r][h]), h = e/64.
// ROUND-11 OVERHAUL (theory: gemm64 is the hidden latency/barrier sink in
// the stable ~99us non-attn residual; grid 512 = only 2 blocks/CU, so the
// old 16-barriers/block + loads-issued-after-barrier structure exposes
// ~600cy of load latency on each of 8 K-iters with no TLP to hide it):
//  1. LDS double-buffer (16->32 KB; blocks/CU is GRID-capped at 2, so no
//     occupancy loss -- unlike round-8's attn dbuf which halved LDS cap).
//     One barrier per K-iter: 16 -> 9 per block.
//  2. Next-iter global loads issued at iter TOP, consumed after the MFMA
//     phase (~400cy extra cover).
//  3. XCD stripe swizzle: d=(y&7)+8*((y>>3)*4+x) puts the 4 column-blocks
//     of each 64-row num-stripe (128 KB) on ONE XCD -> stripe fetched once,
//     re-read from that XCD's L2.
//  4. launch_bounds(256,2) = 128-VGPR cap >= ~75 live (round-2/6 rule).
// ---------------------------------------------------------------------------
__global__ __launch_bounds__(256, 2) void gemm64_ocomb(
    const short* __restrict__ num, const float* __restrict__ lbuf,
    const short* __restrict__ W, const float* __restrict__ bias,
    float* __restrict__ out)
{
    const int K = 512, Ccols = 256;
    const size_t NHALF = (size_t)ROWS * 512;
    const int R8 = ROWS * 8;
    __shared__ short As[2][64 * 64];
    __shared__ short Ws[2][64 * 64];
    const int tid = threadIdx.x;
    const int w = tid >> 6, lane = tid & 63, low = lane & 15, quad = lane >> 4;
    const int wm = w >> 1, wn = w & 1;

    // XCD stripe swizzle: all 4 col-blocks of row-stripe y share d%8 = y&7.
    const int d = blockIdx.x;
    const int c8 = d & 7, j = d >> 3;
    const int xcol = j & 3;
    const int y = ((j >> 2) << 3) + c8;      // 0..127
    const int r0 = y * 64, c0 = xcol * 64;

    const int srow = tid >> 2;
    const int sc = (tid & 3) * 2;

    f32x4 acc[2][2];
#pragma unroll
    for (int mt = 0; mt < 2; ++mt)
#pragma unroll
        for (int nt = 0; nt < 2; ++nt) acc[mt][nt] = (f32x4){0.f, 0.f, 0.f, 0.f};

    uint4 pa1[2], pa2[2];
    float pinv;
    bf16x8 pwb[2];

    auto loadA = [&](int k0) {
        const int hh = k0 >> 6;
        const int row = r0 + srow;
        pinv = lbuf[row * 8 + hh] + lbuf[R8 + row * 8 + hh];
        const short* p1 = num + (size_t)row * 512 + k0 + sc * 8;
        pa1[0] = ((const uint4*)p1)[0];
        pa1[1] = ((const uint4*)p1)[1];
        const short* p2 = p1 + NHALF;
        pa2[0] = ((const uint4*)p2)[0];
        pa2[1] = ((const uint4*)p2)[1];
    };
    auto loadW = [&](int k0) {
        const short* p = W + (size_t)(c0 + srow) * K + k0 + sc * 8;
        pwb[0] = ((const bf16x8*)p)[0];
        pwb[1] = ((const bf16x8*)p)[1];
    };
    auto stage = [&](int bi) {
        const float inv = 1.f / pinv;
#pragma unroll
        for (int c = 0; c < 2; ++c) {
            const int pc = (sc + c) ^ (srow & 7);
            union { unsigned u[4]; bf16x8 v; } r;
            r.u[0] = comb2(pa1[c].x, pa2[c].x, inv);
            r.u[1] = comb2(pa1[c].y, pa2[c].y, inv);
            r.u[2] = comb2(pa1[c].z, pa2[c].z, inv);
            r.u[3] = comb2(pa1[c].w, pa2[c].w, inv);
            *(bf16x8*)(&As[bi][srow * 64 + pc * 8]) = r.v;
            *(bf16x8*)(&Ws[bi][srow * 64 + pc * 8]) = pwb[c];
        }
    };

    // prologue: tile 0 staged into buffer 0
    loadA(0); loadW(0);
    stage(0);
    __syncthreads();

    const int NT = K / 64;   // 8 K-iters
    for (int t = 0; t < NT; ++t) {
        // issue next-tile loads first: covered by this iter's MFMA phase
        if (t + 1 < NT) { loadA((t + 1) * 64); loadW((t + 1) * 64); }

        const short* Ac = &As[t & 1][0];
        const short* Wc = &Ws[t & 1][0];
#pragma unroll
        for (int kh = 0; kh < 2; ++kh) {
            bf16x8 af[2], bfv[2];
#pragma unroll
            for (int tt = 0; tt < 2; ++tt) {
                const int ra = wm * 32 + tt * 16 + low;
                af[tt] = *(const bf16x8*)(&Ac[ra * 64 + ((kh * 4 + quad) ^ (ra & 7)) * 8]);
                const int rb = wn * 32 + tt * 16 + low;
                bfv[tt] = *(const bf16x8*)(&Wc[rb * 64 + ((kh * 4 + quad) ^ (rb & 7)) * 8]);
            }
#pragma unroll
            for (int mt = 0; mt < 2; ++mt)
#pragma unroll
                for (int nt = 0; nt < 2; ++nt)
                    acc[mt][nt] = __builtin_amdgcn_mfma_f32_16x16x32_bf16(af[mt], bfv[nt], acc[mt][nt], 0, 0, 0);
        }

        // stage next tile into the other buffer; ONE barrier per iter.
        // WAR safe: buf (t+1)&1 was last read at iter t-1, before that
        // iter's barrier; RAW safe: writes land before this barrier.
        if (t + 1 < NT) stage((t + 1) & 1);
        __syncthreads();
    }

#pragma unroll
    for (int nt = 0; nt < 2; ++nt) {
        const int col = c0 + wn * 32 + nt * 16 + low;
        const float bv = bias[col];
#pragma unroll
        for (int mt = 0; mt < 2; ++mt) {
            const size_t rbase = (size_t)(r0 + wm * 32 + mt * 16 + quad * 4);
#pragma unroll
            for (int r = 0; r < 4; ++r)
                out[(rbase + r) * Ccols + col] = acc[mt][nt][r] + bv;
        }
    }
}

// ---------------------------------------------------------------------------
// MFMA flash attention (32x32x16): split-K x2 over keys, XCD-swizzled 1-D
// grid, reads pre-projected/pre-scaled q2. Round-1 structure exactly
// (single-buffered Ks/Vt, 2 barriers/iter, coalesced staging, P in regs via
// cvt_pk + v_permlane32_swap_b32): measured 55.4-56.0 us / VGPR 60 / 18KB.
// ATTENTION PLATEAU (rounds 1-9): three clean variants converge --
//   round-1 (4 blk/CU, 2 barriers)       55.4 us  MfmaUtil 24.7 VALU 41.5
//   dbuf 1-barrier (4 blk/CU, 36KB LDS)  70.2 us  (occupancy 30->22, lost)
//   split-K x4 (8 blk/CU)                57.5 us  (occupancy +3% only, null)
// => throughput-bound on the VALU(exp2/pack/permlane)+LDS mix. Keep.
// ROUND-4: K-direct-from-global falsified (uncoalesced, 121.6 us).
// ROUND-2/6: launch_bounds (256,N) caps VGPR ~512/(2N); (256,4)=64 fits 60.
// Layouts (32x32x16, verified m74/m101):
//   A: A[m = lane&31][k = (lane>>5)*8 + j]
//   B: B[k = (lane>>5)*8 + j][n = lane&31]
//   C: col(n) = lane&31, row(m) = (reg&3) + 8*(reg>>2) + 4*(lane>>5)
// ---------------------------------------------------------------------------
#define KST 72
#define VST 72

__global__ __launch_bounds__(256, 4) void attn_mfma(
    const short* __restrict__ q2,   // ROWS x 512 bf16 (pre-scaled)
    const short* __restrict__ kv2,  // ROWS x 1024 bf16
    short* __restrict__ numb,       // 2 x ROWS x 512 bf16 (unnormalized O)
    float* __restrict__ lbuf)       // 2 x ROWS x 8 fp32
{
    __shared__ short Ks[64 * KST];
    __shared__ short Vt[64 * VST];

    const int tid = threadIdx.x;
    const int w = tid >> 6;
    const int lane = tid & 63;
    const int l31 = lane & 31;
    const int h2 = lane >> 5;

    // XCD swizzle decode
    const int flat = blockIdx.x;
    const int h = flat & 7;
    const int rest = flat >> 3;
    const int half = rest & 1;
    const int rest2 = rest >> 1;
    const int qtile = rest2 & 15;
    const int b = rest2 >> 4;
    const int iq0 = qtile * 128;
    const int jt0 = half * 16;

    // --- Q fragments: B operand, 4 k-steps, registers all kernel ---
    bf16x8 qr[4];
#pragma unroll
    for (int st = 0; st < 4; ++st)
        qr[st] = *(const bf16x8*)(q2 + (size_t)(b * SEQ + iq0 + w * 32 + l31) * 512
                                  + h * 64 + st * 16 + h2 * 8);

    const short* kbase = kv2 + (size_t)(b * SEQ) * 1024 + h * 64;
    const short* vbase = kbase + 512;

    float lsum = 0.f;                 // partial: query = l31, this lane's keys
    f32x16 oacc[2];                   // [dg]; col = dim, rows = queries
#pragma unroll
    for (int dg = 0; dg < 2; ++dg)
#pragma unroll
        for (int r = 0; r < 16; ++r) oacc[dg][r] = 0.f;

    // staging indices
    const int krow = tid >> 2;          // key row 0..63
    const int kc = (tid & 3) * 16;      // dim chunk (shorts)
    const int vk4 = (tid & 15) * 4;     // key base (V^T)
    const int vd4 = (tid >> 4) * 4;     // dim base 0..60

    // --- prefetch first tile of this half ---
    bf16x8 pk0, pk1;
    bf16x4 pv0, pv1, pv2, pv3;
    {
        const short* ksrc = kbase + (size_t)(jt0 * 64 + krow) * 1024 + kc;
        pk0 = *(const bf16x8*)(ksrc);
        pk1 = *(const bf16x8*)(ksrc + 8);
        const short* vs = vbase + (size_t)(jt0 * 64 + vk4) * 1024 + vd4;
        pv0 = *(const bf16x4*)(vs);
        pv1 = *(const bf16x4*)(vs + 1024);
        pv2 = *(const bf16x4*)(vs + 2048);
        pv3 = *(const bf16x4*)(vs + 3072);
    }

    for (int jt = jt0; jt < jt0 + 16; ++jt) {
        __syncthreads();
        *(bf16x8*)(&Ks[krow * KST + kc]) = pk0;
        *(bf16x8*)(&Ks[krow * KST + kc + 8]) = pk1;
        {
            bf16x4 c0_, c1_, c2_, c3_;
            c0_[0] = pv0[0]; c0_[1] = pv1[0]; c0_[2] = pv2[0]; c0_[3] = pv3[0];
            c1_[0] = pv0[1]; c1_[1] = pv1[1]; c1_[2] = pv2[1]; c1_[3] = pv3[1];
            c2_[0] = pv0[2]; c2_[1] = pv1[2]; c2_[2] = pv2[2]; c2_[3] = pv3[2];
            c3_[0] = pv0[3]; c3_[1] = pv1[3]; c3_[2] = pv2[3]; c3_[3] = pv3[3];
            *(bf16x4*)(&Vt[(vd4 + 0) * VST + vk4]) = c0_;
            *(bf16x4*)(&Vt[(vd4 + 1) * VST + vk4]) = c1_;
            *(bf16x4*)(&Vt[(vd4 + 2) * VST + vk4]) = c2_;
            *(bf16x4*)(&Vt[(vd4 + 3) * VST + vk4]) = c3_;
        }
        __syncthreads();

        // prefetch next tile
        if (jt + 1 < jt0 + 16) {
            const short* ksrc = kbase + (size_t)((jt + 1) * 64 + krow) * 1024 + kc;
            pk0 = *(const bf16x8*)(ksrc);
            pk1 = *(const bf16x8*)(ksrc + 8);
            const short* vs = vbase + (size_t)((jt + 1) * 64 + vk4) * 1024 + vd4;
            pv0 = *(const bf16x4*)(vs);
            pv1 = *(const bf16x4*)(vs + 1024);
            pv2 = *(const bf16x4*)(vs + 2048);
            pv3 = *(const bf16x4*)(vs + 3072);
        }

        // --- S^T = K Q^T (2 key-groups x 4 k-steps); P stays in registers ---
        bf16x8 pfrag[4];
#pragma unroll
        for (int kg = 0; kg < 2; ++kg) {
            f32x16 s;
#pragma unroll
            for (int r = 0; r < 16; ++r) s[r] = 0.f;
#pragma unroll
            for (int st = 0; st < 4; ++st) {
                const bf16x8 kf = *(const bf16x8*)(&Ks[(kg * 32 + l31) * KST + st * 16 + h2 * 8]);
                s = __builtin_amdgcn_mfma_f32_32x32x16_bf16(kf, qr[st], s, 0, 0, 0);
            }
            // exp2 + pack pairs: wv[2g]   = keys (8g+4*h2, 8g+1+4*h2)
            //                    wv[2g+1] = keys (8g+2+4*h2, 8g+3+4*h2)
            unsigned wv[8];
#pragma unroll
            for (int g = 0; g < 4; ++g) {
                const float p0 = __builtin_amdgcn_exp2f(s[4 * g + 0]);
                const float p1 = __builtin_amdgcn_exp2f(s[4 * g + 1]);
                const float p2 = __builtin_amdgcn_exp2f(s[4 * g + 2]);
                const float p3 = __builtin_amdgcn_exp2f(s[4 * g + 3]);
                lsum += (p0 + p1) + (p2 + p3);
                wv[2 * g]     = pack2bf(p0, p1);
                wv[2 * g + 1] = pack2bf(p2, p3);
            }
            // v_permlane32_swap_b32: lane l <-> l+32 (same query row l31).
            // swap(wv0,wv2) -> A-words 0,2 ; swap(wv1,wv3) -> A-words 1,3
#pragma unroll
            for (int q = 0; q < 2; ++q) {
                unsigned a0 = wv[4 * q + 0], b0 = wv[4 * q + 2];
                unsigned a1 = wv[4 * q + 1], b1 = wv[4 * q + 3];
                asm volatile("v_permlane32_swap_b32 %0, %1" : "+v"(a0), "+v"(b0));
                asm volatile("v_permlane32_swap_b32 %0, %1" : "+v"(a1), "+v"(b1));
                union { unsigned u[4]; bf16x8 v; } f;
                f.u[0] = a0; f.u[1] = a1; f.u[2] = b0; f.u[3] = b1;
                pfrag[kg * 2 + q] = f.v;
            }
        }

        // --- O += P V (4 k-steps x 2 dim-groups), P from registers ---
#pragma unroll
        for (int st = 0; st < 4; ++st) {
            const bf16x8 pf = pfrag[st];
#pragma unroll
            for (int dg = 0; dg < 2; ++dg) {
                const bf16x8 vf = *(const bf16x8*)(&Vt[(dg * 32 + l31) * VST + st * 16 + h2 * 8]);
                oacc[dg] = __builtin_amdgcn_mfma_f32_32x32x16_bf16(pf, vf, oacc[dg], 0, 0, 0);
            }
        }
    }

    // --- epilogue: combine h2 halves of lsum; store partial l and O ---
    lsum += __shfl_xor(lsum, 32);     // all 64 keys for query = w*32 + l31
    short* nb = numb + (size_t)half * ROWS * 512;
    float* lb = lbuf + (size_t)half * ROWS * 8;
    if (lane < 32)
        lb[(size_t)(b * SEQ + iq0 + w * 32 + l31) * 8 + h] = lsum;
#pragma unroll
    for (int dg = 0; dg < 2; ++dg)
#pragma unroll
        for (int r = 0; r < 16; ++r) {
            const int qrow = w * 32 + (r & 3) + 8 * (r >> 2) + 4 * h2;
            nb[(size_t)(b * SEQ + iq0 + qrow) * 512 + h * 64 + dg * 32 + l31] =
                f2bf(oacc[dg][r]);
        }
}

// ---------------------------------------------------------------------------
extern "C" void kernel_launch(void* const* d_in, const int* in_sizes, int n_in,
                              void* d_out, int out_size, void* d_ws, size_t ws_size,
                              hipStream_t stream) {
    const float* x   = (const float*)d_in[0];  // (4,2048,256)
    const float* ctx = (const float*)d_in[1];  // (4,2048,256)
    const float* Wq  = (const float*)d_in[2];  // (512,256)
    const float* bq  = (const float*)d_in[3];
    const float* Wkv = (const float*)d_in[4];  // (1024,256)
    const float* bkv = (const float*)d_in[5];
    const float* Wo  = (const float*)d_in[6];  // (256,512)
    const float* bo  = (const float*)d_in[7];
    float* out = (float*)d_out;                // (4,2048,256) fp32

    short* xb   = (short*)d_ws;                         // ROWS*256
    short* cb   = xb + (size_t)ROWS * 256;              // ROWS*256
    short* wqb  = cb + (size_t)ROWS * 256;              // 131072
    short* wkvb = wqb + 131072;                         // 262144
    short* wob  = wkvb + 262144;                        // 131072
    short* q2b  = wob + 131072;                         // ROWS*512
    short* kv2b = q2b + (size_t)ROWS * 512;             // ROWS*1024
    short* numb = kv2b + (size_t)ROWS * 1024;           // 2*ROWS*512
    float* lbuf = (float*)(numb + (size_t)2 * ROWS * 512); // 2*ROWS*8

    const float qscale = 0.125f * 1.44269504088896f;   // softmax scale + log2e

    cvt_all<<<4608, 256, 0, stream>>>(x, ctx, Wq, Wkv, Wo,
                                      xb, cb, wqb, wkvb, wob);
    // merged q+kv projection, 128x128 tiles, pure bf16 (768 blocks = 3/CU)
    proj2<<<768, 256, 0, stream>>>(xb, wqb, bq, cb, wkvb, bkv,
                                   q2b, kv2b, qscale);
    // attention, split-K x2, 32x32x16 MFMA, XCD-swizzled 1-D grid (1024 blocks)
    attn_mfma<<<NB * NHEADS * (SEQ / 128) * 2, 256, 0, stream>>>(
        q2b, kv2b, numb, lbuf);
    // out = combine(num1,num2)/(l1+l2) * Wo^T + bo (bf16 Wo), dbuf pipeline
    gemm64_ocomb<<<512, 256, 0, stream>>>(numb, lbuf, wob, bo, out);
}